// Round 6
// baseline (9744.545 us; speedup 1.0000x reference)
//
#include <hip/hip_runtime.h>

#define NN 64
#define LDP (NN + 1)  // +1 padding: kills the 32/64-way column-access bank conflicts

// Deflation tolerance: float-storage T has a subdiagonal noise floor of
// ~1.2e-7 * local scale; 5e-7 is ~4x above it (proven R1-R5: absmax 0.03125).
#define DEFL_TOL 5e-7

// Packed upper-Hessenberg band with 3 subdiagonals. Row r stores cols
// max(0,r-3)..63. 2266 floats = 9064 B.
#define BAND_SIZE 2266

__device__ __forceinline__ int rb_of(int r) {
  int t = (r >= 4) ? (((r - 4) * (r - 3)) >> 1) : 0;
  int s = (r >= 3) ? (r - 3) : 0;
  return 64 * r - t - s;
}

__device__ __forceinline__ double guard_d(double p) {
  if (fabs(p) < 1e-280) return (p >= 0.0) ? 1e-280 : -1e-280;
  return p;
}

// Wave-uniform lane read of a double via v_readlane (no LDS, no lgkmcnt).
__device__ __forceinline__ double readlane_d(double v, int l) {
  union { double d; int i[2]; } u;
  u.d = v;
  int a = __builtin_amdgcn_readlane(u.i[0], l);
  int b = __builtin_amdgcn_readlane(u.i[1], l);
  union { double d; int i[2]; } w;
  w.i[0] = a; w.i[1] = b;
  return w.d;
}

// Single-wave workgroup fences (R3-proven). lgkmcnt(0) + clobber for
// cross-lane LDS visibility; sched_barrier stops hoisting (rule #18).
#define WAVE_FENCE()                                   \
  do {                                                 \
    asm volatile("s_waitcnt lgkmcnt(0)" ::: "memory"); \
    __builtin_amdgcn_sched_barrier(0);                 \
  } while (0)
#define VM_FENCE()                                     \
  do {                                                 \
    asm volatile("s_waitcnt vmcnt(0)" ::: "memory");   \
    __builtin_amdgcn_sched_barrier(0);                 \
  } while (0)

// ============================================================================
// Kernel 1: Hessenberg reduction (R3-proven, unchanged). FLOAT-storage T in
// LDS, DOUBLE math. Q (transposed layout Qg[c*64+r]=Q[r][c]) built in d_out.
// ============================================================================
__global__ __launch_bounds__(64) void hess64_kernel(const float* __restrict__ x,
                                                    float* __restrict__ out,
                                                    float* __restrict__ ws) {
  __shared__ float Td[NN][LDP];
  __shared__ double vbuf[NN];

  const int lane = threadIdx.x;
  const size_t mat = blockIdx.x;
  const float* src = x + mat * NN * NN;
  float* Qg = out + mat * NN * NN;
  float* Tg = ws + mat * NN * NN;

  for (int r = 0; r < NN; ++r) Td[r][lane] = src[r * NN + lane];
  for (int c = 0; c < NN; ++c) Qg[c * NN + lane] = (c == lane) ? 1.0f : 0.0f;
  WAVE_FENCE();

  for (int k = 0; k <= NN - 3; ++k) {
    const int m = NN - 1 - k;
    double xt = (lane < m) ? (double)Td[k + 1 + lane][k] : 0.0;
    double ss = xt * xt;
    #pragma unroll
    for (int off = 32; off; off >>= 1) ss += __shfl_xor(ss, off);
    double x0 = (double)Td[k + 1][k];
    if (ss > 1e-280) {  // uniform across wave
      double sg = sqrt(ss);
      double beta = (x0 >= 0.0) ? -sg : sg;
      double tau = 1.0 / (ss - beta * x0);
      vbuf[lane] = (lane < m) ? (xt - ((lane == 0) ? beta : 0.0)) : 0.0;
      WAVE_FENCE();
      if (lane >= k + 1) {  // left apply
        const int j = lane;
        double acc = 0.0;
        for (int t = 0; t < m; ++t) acc += vbuf[t] * (double)Td[k + 1 + t][j];
        acc *= tau;
        for (int t = 0; t < m; ++t)
          Td[k + 1 + t][j] = (float)((double)Td[k + 1 + t][j] - vbuf[t] * acc);
      }
      WAVE_FENCE();
      if (lane == 0) Td[k + 1][k] = (float)beta;
      if (lane >= 1 && lane < m) Td[k + 1 + lane][k] = 0.0f;
      VM_FENCE();  // Q RMW across iterations
      {  // right apply on T (LDS) and Q (global, coalesced, DOUBLE math)
        const int r = lane;
        double acc = 0.0;
        double qa = 0.0;
        for (int t = 0; t < m; ++t) {
          double vt = vbuf[t];
          acc += (double)Td[r][k + 1 + t] * vt;
          qa += (double)Qg[(k + 1 + t) * NN + r] * vt;
        }
        acc *= tau;
        qa *= tau;
        for (int t = 0; t < m; ++t) {
          double vt = vbuf[t];
          Td[r][k + 1 + t] = (float)((double)Td[r][k + 1 + t] - acc * vt);
          Qg[(k + 1 + t) * NN + r] =
              (float)((double)Qg[(k + 1 + t) * NN + r] - qa * vt);
        }
      }
      WAVE_FENCE();
    }
  }

  for (int r = 0; r < NN; ++r) Tg[r * NN + lane] = Td[r][lane];
}

// ============================================================================
// Kernel 2: Francis double-shift QR on packed band.
// R6: SINGLE-FENCE chase step. The left apply (rows k..k+2 x cols>=k) and
// right apply (rows<=rmax x cols k..k+2) interact only through the 3x3 pivot
// block. New step structure: ALL reads up front (one LDS latency exposure),
// left apply in registers, 3x3 block handed to the row role via 9 uniform
// readlane_d (double — strictly tighter than the old float LDS bounce),
// right apply, double handoff, ALL writes, ONE fence. Within a single wave
// LDS instructions execute in program order and the compiler cannot reorder
// potentially-aliasing read->write, so reads-before-writes needs no fence.
// Arithmetic ops/order identical to R5 (proven); only 9 values/step carried
// in double instead of float-rounded.
// R5-kept: hoisted bases, chunked deferred-Q (double math), double chase.
// ============================================================================
#define TD(r, c) band[rb_of(r) + (c)]

__global__ __launch_bounds__(64) void qr64_kernel(float* __restrict__ out,
                                                  float* __restrict__ ws) {
  __shared__ float band[BAND_SIZE];
  __shared__ float recT[NN], recY[NN], recZ[NN];  // normalized reflector stash

  const int lane = threadIdx.x;
  const int myrb = rb_of(lane);                          // per-lane row base
  const int myrb_m1 = (lane >= 1) ? rb_of(lane - 1) : 0; // row above's base
  const size_t mat = blockIdx.x;
  float* Qg = out + mat * NN * NN;
  float* Tg = ws + mat * NN * NN;

  // dense H -> band
  for (int r = 0; r < NN; ++r) {
    int st = (r >= 3) ? (r - 3) : 0;
    if (lane >= st) band[rb_of(r) + lane] = Tg[r * NN + lane];
  }
  WAVE_FENCE();

  int hi = NN - 1;
  int its = 0, total = 0;
  while (hi > 0) {
    bool small = false;
    if (lane >= 1 && lane <= hi) {
      double s = fabs((double)band[myrb_m1 + lane - 1]) + fabs((double)band[myrb + lane]);
      if (s == 0.0) s = 1e-300;
      small = fabs((double)band[myrb + lane - 1]) <= DEFL_TOL * s;
    }
    unsigned long long msk = __ballot(small) | 1ULL;
    if (hi < 63) msk &= (2ULL << hi) - 1ULL;
    const int lo = 63 - __clzll(msk);
    if (lo > 0) {
      if (lane == 0) TD(lo, lo - 1) = 0.0f;
      WAVE_FENCE();
    }
    if (lo == hi) { hi -= 1; its = 0; continue; }
    if (lo == hi - 1) {  // 2x2 window (cold path)
      double a = TD(hi - 1, hi - 1), b = TD(hi - 1, hi);
      double c = TD(hi, hi - 1), d = TD(hi, hi);
      double pp = 0.5 * (a - d);
      double disc = pp * pp + b * c;
      if (disc >= 0.0) {  // real pair: rotate to triangular
        double sq = sqrt(disc);
        double mid = 0.5 * (a + d);
        double lam = mid + ((mid >= 0.0) ? sq : -sq);
        double u0 = b, u1 = lam - a;
        double w0 = lam - d, w1 = c;
        double nu = u0 * u0 + u1 * u1, nw = w0 * w0 + w1 * w1;
        double cs, sn;
        if (nu >= nw && nu > 1e-280) { double n2 = sqrt(nu); cs = u0 / n2; sn = u1 / n2; }
        else if (nw > 1e-280) { double n2 = sqrt(nw); cs = w0 / n2; sn = w1 / n2; }
        else { cs = 1.0; sn = 0.0; }
        {
          const int j = lane;
          const int jmin = (hi >= 2) ? (hi - 2) : 0;  // cols < hi-2 exact 0
          if (j >= jmin) {
            double r0 = TD(hi - 1, j), r1 = TD(hi, j);
            TD(hi - 1, j) = (float)(cs * r0 + sn * r1);
            TD(hi, j) = (float)(cs * r1 - sn * r0);
          }
        }
        WAVE_FENCE();
        {
          const int r = lane;
          if (r <= hi) {
            double c0 = TD(r, hi - 1), c1 = TD(r, hi);
            TD(r, hi - 1) = (float)(cs * c0 + sn * c1);
            TD(r, hi) = (float)(cs * c1 - sn * c0);
          }
        }
        VM_FENCE();  // drain prior deferred-Q stores before Q RMW
        {
          const int r = lane;
          double q0 = (double)Qg[(hi - 1) * NN + r], q1 = (double)Qg[hi * NN + r];
          Qg[(hi - 1) * NN + r] = (float)(cs * q0 + sn * q1);
          Qg[hi * NN + r] = (float)(cs * q1 - sn * q0);
        }
        WAVE_FENCE();
        if (lane == 0) TD(hi, hi - 1) = 0.0f;
        WAVE_FENCE();
      }
      hi -= 2; its = 0; continue;
    }
    ++its; ++total;
    if (its > 40 || total > 2000) {  // safety: force deflation
      if (lane == 0) TD(hi, hi - 1) = 0.0f;
      WAVE_FENCE();
      hi -= 1; its = 0; continue;
    }
    double sa, sb, sc2, sd2;
    if (its == 10 || its == 20 || its == 30) {  // exceptional shift
      double sx = fabs((double)TD(hi, hi - 1)) + fabs((double)TD(hi - 1, hi - 2));
      sa = 0.75 * sx + (double)TD(hi, hi); sb = -0.4375 * sx; sc2 = sx; sd2 = sa;
    } else {
      sa = TD(hi - 1, hi - 1); sb = TD(hi - 1, hi);
      sc2 = TD(hi, hi - 1); sd2 = TD(hi, hi);
    }
    double tr = sa + sd2;
    double det = sa * sd2 - sb * sc2;
    double h11 = TD(lo, lo), h12 = TD(lo, lo + 1), h21 = TD(lo + 1, lo);
    double h22 = TD(lo + 1, lo + 1), h32 = TD(lo + 2, lo + 1);
    double cvx = h11 * h11 + h12 * h21 - tr * h11 + det;
    double cvy = h21 * (h11 + h22 - tr);
    double cvz = h21 * h32;

    int nk = hi - lo;  // reflectors recorded this sweep (uniform register)
    for (int k = lo; k <= hi - 1; ++k) {  // bulge chase — ONE fence per step
      const int rbk = rb_of(k), rbk1 = rb_of(k + 1), rbk2 = rb_of(k + 2);
      const int nr = (k + 2 <= hi) ? 3 : 2;
      const double vx = cvx, vy = cvy, vz = (nr == 3) ? cvz : 0.0;
      double ss2 = vx * vx + vy * vy + vz * vz;
      if (ss2 < 1e-280) { nk = k - lo; break; }  // bulge collapsed
      double sg = sqrt(ss2);
      double beta = (vx >= 0.0) ? -sg : sg;
      double v0 = vx - beta, v1 = vy, v2 = vz;
      double tau = 1.0 / (ss2 - beta * vx);
      if (lane == 0) {  // stash normalized reflector (uniform, O(1)-bounded)
        double iv0 = 1.0 / v0;  // |v0| >= sg > 0 here
        recT[k - lo] = (float)(tau * v0 * v0);
        recY[k - lo] = (float)(v1 * iv0);
        recZ[k - lo] = (float)(v2 * iv0);
      }
      const int j = lane;  // column role
      const int rmax = (k + 3 <= hi) ? (k + 3) : hi;
      const bool inblk = (lane >= k) && (lane < k + nr);
      // ---- ALL reads up front (no LDS writes yet this step) ----
      double t0 = 0.0, t1 = 0.0, t2v = 0.0;
      if (j >= k) {  // column-role: rows k..k+2 at col j
        t0 = (double)band[rbk + j];
        t1 = (double)band[rbk1 + j];
        if (nr == 3) t2v = (double)band[rbk2 + j];
      }
      double c0 = 0.0, c1 = 0.0, c2v = 0.0;
      if (lane <= rmax && !inblk) {  // row-role: cols k..k+2 at row lane
        c0 = (double)band[myrb + k];
        c1 = (double)band[myrb + k + 1];
        if (nr == 3) c2v = (double)band[myrb + k + 2];
      }
      // ---- left apply in registers (column role) ----
      double L0 = 0.0, L1 = 0.0, L2 = 0.0;
      {
        double tt = tau * (v0 * t0 + v1 * t1 + v2 * t2v);
        L0 = t0 - v0 * tt;
        L1 = t1 - v1 * tt;
        L2 = t2v - v2 * tt;
      }
      // ---- 3x3 left-applied pivot block -> row role, via uniform readlanes
      // a{c}{q} = left-applied (row k+q, col k+c), from source lane k+c.
      {
        const int lk1 = k + 1;
        const int lk2 = (k + 2 <= 63) ? (k + 2) : 63;  // clamp; unused if nr==2
        double a00 = readlane_d(L0, k), a10 = readlane_d(L1, k), a20 = readlane_d(L2, k);
        double a01 = readlane_d(L0, lk1), a11 = readlane_d(L1, lk1), a21 = readlane_d(L2, lk1);
        double a02 = readlane_d(L0, lk2), a12 = readlane_d(L1, lk2), a22 = readlane_d(L2, lk2);
        if (inblk) {  // row r = lane = k+q needs (a0q, a1q, a2q)
          c0 = (lane == k) ? a00 : (lane == k + 1) ? a10 : a20;
          c1 = (lane == k) ? a01 : (lane == k + 1) ? a11 : a21;
          c2v = (nr == 3) ? ((lane == k) ? a02 : (lane == k + 1) ? a12 : a22) : 0.0;
        }
      }
      // ---- right apply (row role) ----
      double n0 = 0.0, n1 = 0.0, n2 = 0.0;
      if (lane <= rmax) {
        double tt = tau * (c0 * v0 + c1 * v1 + c2v * v2);
        n0 = c0 - tt * v0;
        n1 = c1 - tt * v1;
        n2 = c2v - tt * v2;
      }
      {  // register handoff of next bulge column (DOUBLE, never rounded)
        const int ly = (k + 2 <= 63) ? (k + 2) : 0;
        const int lz = (k + 3 <= hi) ? (k + 3) : 0;
        cvx = readlane_d(n0, k + 1);
        cvy = readlane_d(n0, ly);
        cvz = readlane_d(n0, lz);
      }
      // ---- ALL writes (reads above are done; same-wave LDS is in-order) ----
      if (j >= k + nr) {  // column-role writes (pivot block owned by row role)
        band[rbk + j] = (float)L0;
        band[rbk1 + j] = (float)L1;
        if (nr == 3) band[rbk2 + j] = (float)L2;
      }
      if (k > lo) {  // exact bulge zeros (col k-1), parallel lanes
        if (lane == 0) band[rbk + (k - 1)] = (float)beta;
        if (lane == 1) band[rbk1 + (k - 1)] = 0.0f;
        if (lane == 2 && nr == 3) band[rbk2 + (k - 1)] = 0.0f;
      }
      if (lane <= rmax) {  // row-role writes (incl. two-sided pivot block)
        band[myrb + k] = (float)n0;
        band[myrb + k + 1] = (float)n1;
        if (nr == 3) band[myrb + k + 2] = (float)n2;
      }
      WAVE_FENCE();
    }

    // ---- deferred Q apply: chunked 16-deep prefetch, DOUBLE math (R5) ----
    VM_FENCE();  // drain prior sweep's Q stores before reloading
    {
      double qw0 = (double)Qg[lo * NN + lane];
      double qw1 = (double)Qg[(lo + 1) * NN + lane];
      double qw2 = (double)Qg[(lo + 2) * NN + lane];
      int done = 0;
      while (done < nk) {
        const int cnt = (nk - done < 16) ? (nk - done) : 16;
        float p[16];
        #pragma unroll
        for (int u = 0; u < 16; ++u) {  // issue all chunk loads together
          const int kc = lo + done + u + 3;
          p[u] = (u < cnt && kc <= hi) ? Qg[kc * NN + lane] : 0.0f;
        }
        #pragma unroll
        for (int u = 0; u < 16; ++u) {
          if (u < cnt) {
            const int i = done + u;
            const double tq = (double)recT[i];
            const double r1 = (double)recY[i];
            const double r2 = (double)recZ[i];
            const double t = tq * (qw0 + qw1 * r1 + qw2 * r2);
            qw0 -= t;
            qw1 -= t * r1;
            qw2 -= t * r2;
            Qg[(lo + i) * NN + lane] = (float)qw0;  // col lo+i final
            qw0 = qw1; qw1 = qw2; qw2 = (double)p[u];
          }
        }
        done += 16;
      }
      if (nk == hi - lo) {
        Qg[hi * NN + lane] = (float)qw0;  // flush last window col
      } else {  // collapsed at k = lo+nk: flush pending window cols
        const int k = lo + nk;
        Qg[k * NN + lane] = (float)qw0;
        Qg[(k + 1) * NN + lane] = (float)qw1;
        if (k + 2 <= hi) Qg[(k + 2) * NN + lane] = (float)qw2;
      }
    }
  }
  WAVE_FENCE();

  // band -> dense Schur T (subdiag + upper only)
  for (int r = 0; r < NN; ++r) {
    float v = 0.0f;
    int st = (r >= 1) ? (r - 1) : 0;
    if (lane >= st) v = band[rb_of(r) + lane];
    Tg[r * NN + lane] = v;
  }
}

// ============================================================================
// Kernel 3: Parlett recurrence + symmetrize + Q Fs Q^T (R2/R3-proven,
// unchanged). 256 threads, 4-thread group per Sylvester pair.
// ============================================================================
__global__ __launch_bounds__(256) void parlett64_kernel(const float* __restrict__ ws,
                                                        float* __restrict__ out) {
  __shared__ float Tfbuf[NN * LDP];
  __shared__ float Fbuf[NN * LDP];
  __shared__ int blkstart[NN];
  __shared__ int bi_of[NN];
  float* Tf = Tfbuf;
  float* Fp = Fbuf;

  const int tid = threadIdx.x;
  const int w = tid >> 6;
  const int lane = tid & 63;
  const size_t mat = blockIdx.x;
  const float* Tg = ws + mat * NN * NN;
  float* dst = out + mat * NN * NN;
  float* Qg = dst;

  #define TF(r, c) ((double)Tf[(r) * LDP + (c)])
  #define FF(r, c) Fp[(r) * LDP + (c)]

  for (int r = w; r < NN; r += 4) Tf[r * LDP + lane] = Tg[r * NN + lane];
  __syncthreads();

  unsigned long long pair_mask =
      __ballot((lane < NN - 1) && (Tf[(lane + 1) * LDP + lane] != 0.0f));
  unsigned long long start_mask = ~(pair_mask << 1);
  const bool isstart = (start_mask >> lane) & 1ULL;
  const bool ispair = (pair_mask >> lane) & 1ULL;
  double fdiag = 0.0, mymod = 1e300;
  if (isstart) {
    if (ispair) {
      double a = TF(lane, lane), b = TF(lane, lane + 1);
      double c = TF(lane + 1, lane), d = TF(lane + 1, lane + 1);
      fdiag = sqrt(fmax(a * d - b * c, 0.0));
    } else {
      fdiag = fabs(TF(lane, lane));
    }
    mymod = fdiag;
  }
  #pragma unroll
  for (int off = 32; off; off >>= 1) mymod = fmin(mymod, __shfl_xor(mymod, off));
  const double cshift = 1e-6 * mymod;

  if (tid < NN) {
    int nb = (int)__popcll(start_mask & ((1ULL << lane) - 1ULL));
    bi_of[lane] = nb;
    if (isstart) blkstart[nb] = lane;
  }
  for (int r = w; r < NN; r += 4) FF(r, lane) = 0.0f;
  __syncthreads();
  if (tid < NN && isstart) {
    FF(lane, lane) = (float)fdiag;
    if (ispair) FF(lane + 1, lane + 1) = (float)fdiag;
  }
  __syncthreads();

  const int sub = lane & 3;
  const int si = (lane & ~3) | w;

  for (int dist = 1; dist < NN; ++dist) {
    const int sj = si + dist;
    bool active = (sj < NN) && ((start_mask >> si) & 1ULL) && ((start_mask >> sj) & 1ULL);
    if (active) {
      const int p = ((pair_mask >> si) & 1ULL) ? 2 : 1;
      const int q = ((pair_mask >> sj) & 1ULL) ? 2 : 1;
      const int bi0 = bi_of[si], bi1 = bi_of[sj];
      double c00 = 0, c01 = 0, c10 = 0, c11 = 0;
      for (int b = bi0 + sub; b < bi1; b += 4) {
        const int k = blkstart[b];
        const bool kp = (pair_mask >> k) & 1ULL;
        double f00 = FF(si, k);
        double f01 = kp ? (double)FF(si, k + 1) : 0.0;
        double f10 = (p == 2) ? (double)FF(si + 1, k) : 0.0;
        double f11 = (p == 2 && kp) ? (double)FF(si + 1, k + 1) : 0.0;
        double t00 = TF(k, sj);
        double t01 = (q == 2) ? TF(k, sj + 1) : 0.0;
        double t10 = kp ? TF(k + 1, sj) : 0.0;
        double t11 = (kp && q == 2) ? TF(k + 1, sj + 1) : 0.0;
        c00 += f00 * t00 + f01 * t10;
        c01 += f00 * t01 + f01 * t11;
        c10 += f10 * t00 + f11 * t10;
        c11 += f10 * t01 + f11 * t11;
      }
      for (int b = bi0 + 1 + sub; b <= bi1; b += 4) {
        const int k = blkstart[b];
        const bool kp = (pair_mask >> k) & 1ULL;
        double t00 = TF(si, k);
        double t01 = kp ? TF(si, k + 1) : 0.0;
        double t10 = (p == 2) ? TF(si + 1, k) : 0.0;
        double t11 = (p == 2 && kp) ? TF(si + 1, k + 1) : 0.0;
        double f00 = FF(k, sj);
        double f01 = (q == 2) ? (double)FF(k, sj + 1) : 0.0;
        double f10 = kp ? (double)FF(k + 1, sj) : 0.0;
        double f11 = (kp && q == 2) ? (double)FF(k + 1, sj + 1) : 0.0;
        c00 -= t00 * f00 + t01 * f10;
        c01 -= t00 * f01 + t01 * f11;
        c10 -= t10 * f00 + t11 * f10;
        c11 -= t10 * f01 + t11 * f11;
      }
      c00 += __shfl_xor(c00, 1); c00 += __shfl_xor(c00, 2);
      c01 += __shfl_xor(c01, 1); c01 += __shfl_xor(c01, 2);
      c10 += __shfl_xor(c10, 1); c10 += __shfl_xor(c10, 2);
      c11 += __shfl_xor(c11, 1); c11 += __shfl_xor(c11, 2);
      if (sub == 0) {
        double x00 = 0, x01 = 0, x10 = 0, x11 = 0;
        if (p == 1 && q == 1) {
          x00 = c00 / guard_d(TF(si, si) - TF(sj, sj));
        } else if (p == 2 && q == 1) {
          double t = TF(sj, sj);
          double m00 = TF(si, si) - t, m01 = TF(si, si + 1);
          double m10 = TF(si + 1, si), m11 = TF(si + 1, si + 1) - t;
          double dd = guard_d(m00 * m11 - m01 * m10);
          x00 = (m11 * c00 - m01 * c10) / dd;
          x10 = (m00 * c10 - m10 * c00) / dd;
        } else if (p == 1 && q == 2) {
          double t = TF(si, si);
          double m00 = t - TF(sj, sj), m01 = -TF(sj, sj + 1);
          double m10 = -TF(sj + 1, sj), m11 = t - TF(sj + 1, sj + 1);
          double dd = guard_d(m00 * m11 - m01 * m10);
          x00 = (c00 * m11 - c01 * m10) / dd;
          x01 = (c01 * m00 - c00 * m01) / dd;
        } else {
          double A00 = TF(si, si), A01 = TF(si, si + 1);
          double A10 = TF(si + 1, si), A11 = TF(si + 1, si + 1);
          double B00 = TF(sj, sj), B01 = TF(sj, sj + 1);
          double B10 = TF(sj + 1, sj), B11 = TF(sj + 1, sj + 1);
          double M[4][5] = {
              {A00 - B00, A01, -B10, 0.0, c00},
              {A10, A11 - B00, 0.0, -B10, c10},
              {-B01, 0.0, A00 - B11, A01, c01},
              {0.0, -B01, A10, A11 - B11, c11}};
          #pragma unroll
          for (int cc = 0; cc < 4; ++cc) {
            #pragma unroll
            for (int rr2 = cc + 1; rr2 < 4; ++rr2) {
              bool sw = fabs(M[rr2][cc]) > fabs(M[cc][cc]);
              #pragma unroll
              for (int t2 = cc; t2 < 5; ++t2) {
                double aa = M[cc][t2], bb = M[rr2][t2];
                M[cc][t2] = sw ? bb : aa;
                M[rr2][t2] = sw ? aa : bb;
              }
            }
            double inv = 1.0 / guard_d(M[cc][cc]);
            #pragma unroll
            for (int rr2 = cc + 1; rr2 < 4; ++rr2) {
              double f2 = M[rr2][cc] * inv;
              #pragma unroll
              for (int t2 = cc; t2 < 5; ++t2) M[rr2][t2] -= f2 * M[cc][t2];
            }
          }
          double z3 = M[3][4] / guard_d(M[3][3]);
          double z2 = (M[2][4] - M[2][3] * z3) / guard_d(M[2][2]);
          double z1 = (M[1][4] - M[1][3] * z3 - M[1][2] * z2) / guard_d(M[1][1]);
          double z0 = (M[0][4] - M[0][3] * z3 - M[0][2] * z2 - M[0][1] * z1) / guard_d(M[0][0]);
          x00 = z0; x10 = z1; x01 = z2; x11 = z3;
        }
        FF(si, sj) = (float)x00;
        if (q == 2) FF(si, sj + 1) = (float)x01;
        if (p == 2) {
          FF(si + 1, sj) = (float)x10;
          if (q == 2) FF(si + 1, sj + 1) = (float)x11;
        }
      }
    }
    __syncthreads();
  }

  {
    const int r = lane;
    for (int j = r + 1 + w; j < NN; j += 4) {
      float v = 0.5f * (FF(r, j) + FF(j, r));
      FF(r, j) = v;
      FF(j, r) = v;
    }
    if (w == 0) FF(r, r) += (float)cshift;
  }
  __syncthreads();

  float* Qs = Tf;  // T dead after Parlett
  for (int c = w; c < NN; c += 4) Qs[lane * LDP + c] = Qg[c * NN + lane];
  __syncthreads();

  float acc[16];
  const int r0 = w * 16;
  #pragma unroll
  for (int i = 0; i < 16; ++i) acc[i] = 0.0f;
  for (int k = 0; k < NN; ++k) {
    float f = FF(k, lane);
    #pragma unroll
    for (int i = 0; i < 16; ++i) acc[i] += Qs[(r0 + i) * LDP + k] * f;
  }
  __syncthreads();
  float* W = Fp;
  #pragma unroll
  for (int i = 0; i < 16; ++i) W[(r0 + i) * LDP + lane] = acc[i];
  __syncthreads();

  #pragma unroll
  for (int i = 0; i < 16; ++i) acc[i] = 0.0f;
  for (int k = 0; k < NN; ++k) {
    float qv = Qs[lane * LDP + k];
    #pragma unroll
    for (int i = 0; i < 16; ++i) acc[i] += W[(r0 + i) * LDP + k] * qv;
  }
  #pragma unroll
  for (int i = 0; i < 16; ++i) dst[(r0 + i) * NN + lane] = acc[i];

  #undef TF
  #undef FF
}

extern "C" void kernel_launch(void* const* d_in, const int* in_sizes, int n_in,
                              void* d_out, int out_size, void* d_ws, size_t ws_size,
                              hipStream_t stream) {
  const float* x = (const float*)d_in[0];
  float* out = (float*)d_out;
  float* ws = (float*)d_ws;  // nmat*64*64*4 B = 64 MB dense T handoff
  const int nmat = in_sizes[0] / (NN * NN);  // 4096
  hess64_kernel<<<nmat, 64, 0, stream>>>(x, out, ws);
  qr64_kernel<<<nmat, 64, 0, stream>>>(out, ws);
  parlett64_kernel<<<nmat, 256, 0, stream>>>(ws, out);
}

// Round 7
// 7468.607 us; speedup vs baseline: 1.3047x; 1.3047x over previous
//
#include <hip/hip_runtime.h>

#define NN 64
#define LDP (NN + 1)  // +1 padding: kills the 32/64-way column-access bank conflicts

// Deflation tolerance. R1-R5 used 5e-7 (4x the float-T noise floor). R7: 1e-5
// — eigenvalue perturbation ~1e-5 * scale(~30) ~ 3e-4 absolute, output error
// ~1e-3 vs threshold 0.251. Deflates each pair ~1 sweep earlier (quadratic
// subdiagonal decay) -> ~25-35% fewer chase steps.
#define DEFL_TOL 1e-5

// Packed upper-Hessenberg band with 3 subdiagonals. Row r stores cols
// max(0,r-3)..63. 2266 floats = 9064 B.
#define BAND_SIZE 2266

__device__ __forceinline__ int rb_of(int r) {
  int t = (r >= 4) ? (((r - 4) * (r - 3)) >> 1) : 0;
  int s = (r >= 3) ? (r - 3) : 0;
  return 64 * r - t - s;
}

__device__ __forceinline__ double guard_d(double p) {
  if (fabs(p) < 1e-280) return (p >= 0.0) ? 1e-280 : -1e-280;
  return p;
}

// Wave-uniform lane read of a double via v_readlane (no LDS, no lgkmcnt).
__device__ __forceinline__ double readlane_d(double v, int l) {
  union { double d; int i[2]; } u;
  u.d = v;
  int a = __builtin_amdgcn_readlane(u.i[0], l);
  int b = __builtin_amdgcn_readlane(u.i[1], l);
  union { double d; int i[2]; } w;
  w.i[0] = a; w.i[1] = b;
  return w.d;
}

// R7: NO explicit LDS fences in the single-wave kernels. Rationale: each
// block is ONE wave; the LDS pipeline processes a wave's DS ops IN ORDER,
// and the compiler preserves program order between potentially-aliasing
// __shared__ accesses (runtime indices). Cross-lane write->read therefore
// needs no lgkmcnt drain; the compiler's automatic waitcnt-before-use covers
// register deps. Global Q RMW still needs vmcnt ordering (store buffer):
#define VM_FENCE()                                     \
  do {                                                 \
    asm volatile("s_waitcnt vmcnt(0)" ::: "memory");   \
    __builtin_amdgcn_sched_barrier(0);                 \
  } while (0)

// ============================================================================
// Kernel 1: Hessenberg reduction. FLOAT-storage T in LDS, DOUBLE math
// (R1-R5-proven). Fence-free (single-wave in-order DS). Q (transposed layout
// Qg[c*64+r]=Q[r][c]) built in d_out.
// ============================================================================
__global__ __launch_bounds__(64) void hess64_kernel(const float* __restrict__ x,
                                                    float* __restrict__ out,
                                                    float* __restrict__ ws) {
  __shared__ float Td[NN][LDP];
  __shared__ double vbuf[NN];

  const int lane = threadIdx.x;
  const size_t mat = blockIdx.x;
  const float* src = x + mat * NN * NN;
  float* Qg = out + mat * NN * NN;
  float* Tg = ws + mat * NN * NN;

  for (int r = 0; r < NN; ++r) Td[r][lane] = src[r * NN + lane];
  for (int c = 0; c < NN; ++c) Qg[c * NN + lane] = (c == lane) ? 1.0f : 0.0f;

  for (int k = 0; k <= NN - 3; ++k) {
    const int m = NN - 1 - k;
    double xt = (lane < m) ? (double)Td[k + 1 + lane][k] : 0.0;
    double ss = xt * xt;
    #pragma unroll
    for (int off = 32; off; off >>= 1) ss += __shfl_xor(ss, off);
    double x0 = (double)Td[k + 1][k];
    if (ss > 1e-280) {  // uniform across wave
      double sg = sqrt(ss);
      double beta = (x0 >= 0.0) ? -sg : sg;
      double tau = 1.0 / (ss - beta * x0);
      vbuf[lane] = (lane < m) ? (xt - ((lane == 0) ? beta : 0.0)) : 0.0;
      if (lane >= k + 1) {  // left apply
        const int j = lane;
        double acc = 0.0;
        for (int t = 0; t < m; ++t) acc += vbuf[t] * (double)Td[k + 1 + t][j];
        acc *= tau;
        for (int t = 0; t < m; ++t)
          Td[k + 1 + t][j] = (float)((double)Td[k + 1 + t][j] - vbuf[t] * acc);
      }
      if (lane == 0) Td[k + 1][k] = (float)beta;
      if (lane >= 1 && lane < m) Td[k + 1 + lane][k] = 0.0f;
      VM_FENCE();  // Q RMW: iteration k-1's stores vs this iteration's loads
      {  // right apply on T (LDS) and Q (global, coalesced, DOUBLE math)
        const int r = lane;
        double acc = 0.0;
        double qa = 0.0;
        for (int t = 0; t < m; ++t) {
          double vt = vbuf[t];
          acc += (double)Td[r][k + 1 + t] * vt;
          qa += (double)Qg[(k + 1 + t) * NN + r] * vt;
        }
        acc *= tau;
        qa *= tau;
        for (int t = 0; t < m; ++t) {
          double vt = vbuf[t];
          Td[r][k + 1 + t] = (float)((double)Td[r][k + 1 + t] - acc * vt);
          Qg[(k + 1 + t) * NN + r] =
              (float)((double)Qg[(k + 1 + t) * NN + r] - qa * vt);
        }
      }
    }
  }

  for (int r = 0; r < NN; ++r) Tg[r * NN + lane] = Td[r][lane];
}

// ============================================================================
// Kernel 2: Francis double-shift QR on packed band. R5-proven structure
// (double-math chase, double handoff, hoisted bases, chunked deferred-Q)
// with the explicit LDS fences removed (single-wave in-order DS) and
// DEFL_TOL loosened to 1e-5 (fewer sweeps).
// ============================================================================
#define TD(r, c) band[rb_of(r) + (c)]

__global__ __launch_bounds__(64) void qr64_kernel(float* __restrict__ out,
                                                  float* __restrict__ ws) {
  __shared__ float band[BAND_SIZE];
  __shared__ float recT[NN], recY[NN], recZ[NN];  // normalized reflector stash

  const int lane = threadIdx.x;
  const int myrb = rb_of(lane);                          // per-lane row base
  const int myrb_m1 = (lane >= 1) ? rb_of(lane - 1) : 0; // row above's base
  const size_t mat = blockIdx.x;
  float* Qg = out + mat * NN * NN;
  float* Tg = ws + mat * NN * NN;

  // dense H -> band
  for (int r = 0; r < NN; ++r) {
    int st = (r >= 3) ? (r - 3) : 0;
    if (lane >= st) band[rb_of(r) + lane] = Tg[r * NN + lane];
  }

  int hi = NN - 1;
  int its = 0, total = 0;
  while (hi > 0) {
    bool small = false;
    if (lane >= 1 && lane <= hi) {
      double s = fabs((double)band[myrb_m1 + lane - 1]) + fabs((double)band[myrb + lane]);
      if (s == 0.0) s = 1e-300;
      small = fabs((double)band[myrb + lane - 1]) <= DEFL_TOL * s;
    }
    unsigned long long msk = __ballot(small) | 1ULL;
    if (hi < 63) msk &= (2ULL << hi) - 1ULL;
    const int lo = 63 - __clzll(msk);
    if (lo > 0) {
      if (lane == 0) TD(lo, lo - 1) = 0.0f;
    }
    if (lo == hi) { hi -= 1; its = 0; continue; }
    if (lo == hi - 1) {  // 2x2 window (cold path)
      double a = TD(hi - 1, hi - 1), b = TD(hi - 1, hi);
      double c = TD(hi, hi - 1), d = TD(hi, hi);
      double pp = 0.5 * (a - d);
      double disc = pp * pp + b * c;
      if (disc >= 0.0) {  // real pair: rotate to triangular
        double sq = sqrt(disc);
        double mid = 0.5 * (a + d);
        double lam = mid + ((mid >= 0.0) ? sq : -sq);
        double u0 = b, u1 = lam - a;
        double w0 = lam - d, w1 = c;
        double nu = u0 * u0 + u1 * u1, nw = w0 * w0 + w1 * w1;
        double cs, sn;
        if (nu >= nw && nu > 1e-280) { double n2 = sqrt(nu); cs = u0 / n2; sn = u1 / n2; }
        else if (nw > 1e-280) { double n2 = sqrt(nw); cs = w0 / n2; sn = w1 / n2; }
        else { cs = 1.0; sn = 0.0; }
        {
          const int j = lane;
          const int jmin = (hi >= 2) ? (hi - 2) : 0;  // cols < hi-2 exact 0
          if (j >= jmin) {
            double r0 = TD(hi - 1, j), r1 = TD(hi, j);
            TD(hi - 1, j) = (float)(cs * r0 + sn * r1);
            TD(hi, j) = (float)(cs * r1 - sn * r0);
          }
        }
        {
          const int r = lane;
          if (r <= hi) {
            double c0 = TD(r, hi - 1), c1 = TD(r, hi);
            TD(r, hi - 1) = (float)(cs * c0 + sn * c1);
            TD(r, hi) = (float)(cs * c1 - sn * c0);
          }
        }
        VM_FENCE();  // drain prior deferred-Q stores before Q RMW
        {
          const int r = lane;
          double q0 = (double)Qg[(hi - 1) * NN + r], q1 = (double)Qg[hi * NN + r];
          Qg[(hi - 1) * NN + r] = (float)(cs * q0 + sn * q1);
          Qg[hi * NN + r] = (float)(cs * q1 - sn * q0);
        }
        if (lane == 0) TD(hi, hi - 1) = 0.0f;
      }
      hi -= 2; its = 0; continue;
    }
    ++its; ++total;
    if (its > 40 || total > 2000) {  // safety: force deflation
      if (lane == 0) TD(hi, hi - 1) = 0.0f;
      hi -= 1; its = 0; continue;
    }
    double sa, sb, sc2, sd2;
    if (its == 10 || its == 20 || its == 30) {  // exceptional shift
      double sx = fabs((double)TD(hi, hi - 1)) + fabs((double)TD(hi - 1, hi - 2));
      sa = 0.75 * sx + (double)TD(hi, hi); sb = -0.4375 * sx; sc2 = sx; sd2 = sa;
    } else {
      sa = TD(hi - 1, hi - 1); sb = TD(hi - 1, hi);
      sc2 = TD(hi, hi - 1); sd2 = TD(hi, hi);
    }
    double tr = sa + sd2;
    double det = sa * sd2 - sb * sc2;
    double h11 = TD(lo, lo), h12 = TD(lo, lo + 1), h21 = TD(lo + 1, lo);
    double h22 = TD(lo + 1, lo + 1), h32 = TD(lo + 2, lo + 1);
    double cvx = h11 * h11 + h12 * h21 - tr * h11 + det;
    double cvy = h21 * (h11 + h22 - tr);
    double cvz = h21 * h32;

    int nk = hi - lo;  // reflectors recorded this sweep (uniform register)
    for (int k = lo; k <= hi - 1; ++k) {  // bulge chase — T only, DOUBLE math
      const int rbk = rb_of(k), rbk1 = rb_of(k + 1), rbk2 = rb_of(k + 2);
      const int nr = (k + 2 <= hi) ? 3 : 2;
      const double vx = cvx, vy = cvy, vz = (nr == 3) ? cvz : 0.0;
      double ss2 = vx * vx + vy * vy + vz * vz;
      if (ss2 < 1e-280) { nk = k - lo; break; }  // bulge collapsed
      double sg = sqrt(ss2);
      double beta = (vx >= 0.0) ? -sg : sg;
      double v0 = vx - beta, v1 = vy, v2 = vz;
      double tau = 1.0 / (ss2 - beta * vx);
      if (lane == 0) {  // stash normalized reflector (uniform, O(1)-bounded)
        double iv0 = 1.0 / v0;  // |v0| >= sg > 0 here
        recT[k - lo] = (float)(tau * v0 * v0);
        recY[k - lo] = (float)(v1 * iv0);
        recZ[k - lo] = (float)(v2 * iv0);
      }
      const int jlo = (k > lo) ? k : lo;
      if (lane >= jlo) {  // left apply
        const int j = lane;
        double t0 = band[rbk + j], t1 = band[rbk1 + j];
        double t2v = (nr == 3) ? (double)band[rbk2 + j] : 0.0;
        double tt = tau * (v0 * t0 + v1 * t1 + v2 * t2v);
        band[rbk + j] = (float)(t0 - v0 * tt);
        band[rbk1 + j] = (float)(t1 - v1 * tt);
        if (nr == 3) band[rbk2 + j] = (float)(t2v - v2 * tt);
      }
      if (lane == 0 && k > lo) {  // exact bulge zeros (col k-1)
        band[rbk + (k - 1)] = (float)beta;
        band[rbk1 + (k - 1)] = 0.0f;
        if (nr == 3) band[rbk2 + (k - 1)] = 0.0f;
      }
      const int rmax = (k + 3 <= hi) ? (k + 3) : hi;
      double n0 = 0.0, n1 = 0.0, n2 = 0.0;
      if (lane <= rmax) {  // right apply (reads left-applied pivot: in-order DS)
        double c0 = band[myrb + k], c1 = band[myrb + k + 1];
        double c2v = (nr == 3) ? (double)band[myrb + k + 2] : 0.0;
        double tt = tau * (c0 * v0 + c1 * v1 + c2v * v2);
        n0 = c0 - tt * v0;
        n1 = c1 - tt * v1;
        n2 = c2v - tt * v2;
      }
      {  // register handoff of next bulge column (DOUBLE, never rounded)
        const int ly = (k + 2 <= 63) ? (k + 2) : 0;
        const int lz = (k + 3 <= hi) ? (k + 3) : 0;
        cvx = readlane_d(n0, k + 1);
        cvy = readlane_d(n0, ly);
        cvz = readlane_d(n0, lz);
      }
      if (lane <= rmax) {
        band[myrb + k] = (float)n0;
        band[myrb + k + 1] = (float)n1;
        if (nr == 3) band[myrb + k + 2] = (float)n2;
      }
    }

    // ---- deferred Q apply: chunked 16-deep prefetch, DOUBLE math (R5) ----
    VM_FENCE();  // drain prior sweep's Q stores before reloading
    {
      double qw0 = (double)Qg[lo * NN + lane];
      double qw1 = (double)Qg[(lo + 1) * NN + lane];
      double qw2 = (double)Qg[(lo + 2) * NN + lane];
      int done = 0;
      while (done < nk) {
        const int cnt = (nk - done < 16) ? (nk - done) : 16;
        float p[16];
        #pragma unroll
        for (int u = 0; u < 16; ++u) {  // issue all chunk loads together
          const int kc = lo + done + u + 3;
          p[u] = (u < cnt && kc <= hi) ? Qg[kc * NN + lane] : 0.0f;
        }
        #pragma unroll
        for (int u = 0; u < 16; ++u) {
          if (u < cnt) {
            const int i = done + u;
            const double tq = (double)recT[i];
            const double r1 = (double)recY[i];
            const double r2 = (double)recZ[i];
            const double t = tq * (qw0 + qw1 * r1 + qw2 * r2);
            qw0 -= t;
            qw1 -= t * r1;
            qw2 -= t * r2;
            Qg[(lo + i) * NN + lane] = (float)qw0;  // col lo+i final
            qw0 = qw1; qw1 = qw2; qw2 = (double)p[u];
          }
        }
        done += 16;
      }
      if (nk == hi - lo) {
        Qg[hi * NN + lane] = (float)qw0;  // flush last window col
      } else {  // collapsed at k = lo+nk: flush pending window cols
        const int k = lo + nk;
        Qg[k * NN + lane] = (float)qw0;
        Qg[(k + 1) * NN + lane] = (float)qw1;
        if (k + 2 <= hi) Qg[(k + 2) * NN + lane] = (float)qw2;
      }
    }
  }

  // band -> dense Schur T (subdiag + upper only)
  for (int r = 0; r < NN; ++r) {
    float v = 0.0f;
    int st = (r >= 1) ? (r - 1) : 0;
    if (lane >= st) v = band[rb_of(r) + lane];
    Tg[r * NN + lane] = v;
  }
}

// ============================================================================
// Kernel 3: Parlett recurrence + symmetrize + Q Fs Q^T (R2-R5-proven,
// unchanged; multi-wave -> keeps __syncthreads).
// ============================================================================
__global__ __launch_bounds__(256) void parlett64_kernel(const float* __restrict__ ws,
                                                        float* __restrict__ out) {
  __shared__ float Tfbuf[NN * LDP];
  __shared__ float Fbuf[NN * LDP];
  __shared__ int blkstart[NN];
  __shared__ int bi_of[NN];
  float* Tf = Tfbuf;
  float* Fp = Fbuf;

  const int tid = threadIdx.x;
  const int w = tid >> 6;
  const int lane = tid & 63;
  const size_t mat = blockIdx.x;
  const float* Tg = ws + mat * NN * NN;
  float* dst = out + mat * NN * NN;
  float* Qg = dst;

  #define TF(r, c) ((double)Tf[(r) * LDP + (c)])
  #define FF(r, c) Fp[(r) * LDP + (c)]

  for (int r = w; r < NN; r += 4) Tf[r * LDP + lane] = Tg[r * NN + lane];
  __syncthreads();

  unsigned long long pair_mask =
      __ballot((lane < NN - 1) && (Tf[(lane + 1) * LDP + lane] != 0.0f));
  unsigned long long start_mask = ~(pair_mask << 1);
  const bool isstart = (start_mask >> lane) & 1ULL;
  const bool ispair = (pair_mask >> lane) & 1ULL;
  double fdiag = 0.0, mymod = 1e300;
  if (isstart) {
    if (ispair) {
      double a = TF(lane, lane), b = TF(lane, lane + 1);
      double c = TF(lane + 1, lane), d = TF(lane + 1, lane + 1);
      fdiag = sqrt(fmax(a * d - b * c, 0.0));
    } else {
      fdiag = fabs(TF(lane, lane));
    }
    mymod = fdiag;
  }
  #pragma unroll
  for (int off = 32; off; off >>= 1) mymod = fmin(mymod, __shfl_xor(mymod, off));
  const double cshift = 1e-6 * mymod;

  if (tid < NN) {
    int nb = (int)__popcll(start_mask & ((1ULL << lane) - 1ULL));
    bi_of[lane] = nb;
    if (isstart) blkstart[nb] = lane;
  }
  for (int r = w; r < NN; r += 4) FF(r, lane) = 0.0f;
  __syncthreads();
  if (tid < NN && isstart) {
    FF(lane, lane) = (float)fdiag;
    if (ispair) FF(lane + 1, lane + 1) = (float)fdiag;
  }
  __syncthreads();

  const int sub = lane & 3;
  const int si = (lane & ~3) | w;

  for (int dist = 1; dist < NN; ++dist) {
    const int sj = si + dist;
    bool active = (sj < NN) && ((start_mask >> si) & 1ULL) && ((start_mask >> sj) & 1ULL);
    if (active) {
      const int p = ((pair_mask >> si) & 1ULL) ? 2 : 1;
      const int q = ((pair_mask >> sj) & 1ULL) ? 2 : 1;
      const int bi0 = bi_of[si], bi1 = bi_of[sj];
      double c00 = 0, c01 = 0, c10 = 0, c11 = 0;
      for (int b = bi0 + sub; b < bi1; b += 4) {
        const int k = blkstart[b];
        const bool kp = (pair_mask >> k) & 1ULL;
        double f00 = FF(si, k);
        double f01 = kp ? (double)FF(si, k + 1) : 0.0;
        double f10 = (p == 2) ? (double)FF(si + 1, k) : 0.0;
        double f11 = (p == 2 && kp) ? (double)FF(si + 1, k + 1) : 0.0;
        double t00 = TF(k, sj);
        double t01 = (q == 2) ? TF(k, sj + 1) : 0.0;
        double t10 = kp ? TF(k + 1, sj) : 0.0;
        double t11 = (kp && q == 2) ? TF(k + 1, sj + 1) : 0.0;
        c00 += f00 * t00 + f01 * t10;
        c01 += f00 * t01 + f01 * t11;
        c10 += f10 * t00 + f11 * t10;
        c11 += f10 * t01 + f11 * t11;
      }
      for (int b = bi0 + 1 + sub; b <= bi1; b += 4) {
        const int k = blkstart[b];
        const bool kp = (pair_mask >> k) & 1ULL;
        double t00 = TF(si, k);
        double t01 = kp ? TF(si, k + 1) : 0.0;
        double t10 = (p == 2) ? TF(si + 1, k) : 0.0;
        double t11 = (p == 2 && kp) ? TF(si + 1, k + 1) : 0.0;
        double f00 = FF(k, sj);
        double f01 = (q == 2) ? (double)FF(k, sj + 1) : 0.0;
        double f10 = kp ? (double)FF(k + 1, sj) : 0.0;
        double f11 = (kp && q == 2) ? (double)FF(k + 1, sj + 1) : 0.0;
        c00 -= t00 * f00 + t01 * f10;
        c01 -= t00 * f01 + t01 * f11;
        c10 -= t10 * f00 + t11 * f10;
        c11 -= t10 * f01 + t11 * f11;
      }
      c00 += __shfl_xor(c00, 1); c00 += __shfl_xor(c00, 2);
      c01 += __shfl_xor(c01, 1); c01 += __shfl_xor(c01, 2);
      c10 += __shfl_xor(c10, 1); c10 += __shfl_xor(c10, 2);
      c11 += __shfl_xor(c11, 1); c11 += __shfl_xor(c11, 2);
      if (sub == 0) {
        double x00 = 0, x01 = 0, x10 = 0, x11 = 0;
        if (p == 1 && q == 1) {
          x00 = c00 / guard_d(TF(si, si) - TF(sj, sj));
        } else if (p == 2 && q == 1) {
          double t = TF(sj, sj);
          double m00 = TF(si, si) - t, m01 = TF(si, si + 1);
          double m10 = TF(si + 1, si), m11 = TF(si + 1, si + 1) - t;
          double dd = guard_d(m00 * m11 - m01 * m10);
          x00 = (m11 * c00 - m01 * c10) / dd;
          x10 = (m00 * c10 - m10 * c00) / dd;
        } else if (p == 1 && q == 2) {
          double t = TF(si, si);
          double m00 = t - TF(sj, sj), m01 = -TF(sj, sj + 1);
          double m10 = -TF(sj + 1, sj), m11 = t - TF(sj + 1, sj + 1);
          double dd = guard_d(m00 * m11 - m01 * m10);
          x00 = (c00 * m11 - c01 * m10) / dd;
          x01 = (c01 * m00 - c00 * m01) / dd;
        } else {
          double A00 = TF(si, si), A01 = TF(si, si + 1);
          double A10 = TF(si + 1, si), A11 = TF(si + 1, si + 1);
          double B00 = TF(sj, sj), B01 = TF(sj, sj + 1);
          double B10 = TF(sj + 1, sj), B11 = TF(sj + 1, sj + 1);
          double M[4][5] = {
              {A00 - B00, A01, -B10, 0.0, c00},
              {A10, A11 - B00, 0.0, -B10, c10},
              {-B01, 0.0, A00 - B11, A01, c01},
              {0.0, -B01, A10, A11 - B11, c11}};
          #pragma unroll
          for (int cc = 0; cc < 4; ++cc) {
            #pragma unroll
            for (int rr2 = cc + 1; rr2 < 4; ++rr2) {
              bool sw = fabs(M[rr2][cc]) > fabs(M[cc][cc]);
              #pragma unroll
              for (int t2 = cc; t2 < 5; ++t2) {
                double aa = M[cc][t2], bb = M[rr2][t2];
                M[cc][t2] = sw ? bb : aa;
                M[rr2][t2] = sw ? aa : bb;
              }
            }
            double inv = 1.0 / guard_d(M[cc][cc]);
            #pragma unroll
            for (int rr2 = cc + 1; rr2 < 4; ++rr2) {
              double f2 = M[rr2][cc] * inv;
              #pragma unroll
              for (int t2 = cc; t2 < 5; ++t2) M[rr2][t2] -= f2 * M[cc][t2];
            }
          }
          double z3 = M[3][4] / guard_d(M[3][3]);
          double z2 = (M[2][4] - M[2][3] * z3) / guard_d(M[2][2]);
          double z1 = (M[1][4] - M[1][3] * z3 - M[1][2] * z2) / guard_d(M[1][1]);
          double z0 = (M[0][4] - M[0][3] * z3 - M[0][2] * z2 - M[0][1] * z1) / guard_d(M[0][0]);
          x00 = z0; x10 = z1; x01 = z2; x11 = z3;
        }
        FF(si, sj) = (float)x00;
        if (q == 2) FF(si, sj + 1) = (float)x01;
        if (p == 2) {
          FF(si + 1, sj) = (float)x10;
          if (q == 2) FF(si + 1, sj + 1) = (float)x11;
        }
      }
    }
    __syncthreads();
  }

  {
    const int r = lane;
    for (int j = r + 1 + w; j < NN; j += 4) {
      float v = 0.5f * (FF(r, j) + FF(j, r));
      FF(r, j) = v;
      FF(j, r) = v;
    }
    if (w == 0) FF(r, r) += (float)cshift;
  }
  __syncthreads();

  float* Qs = Tf;  // T dead after Parlett
  for (int c = w; c < NN; c += 4) Qs[lane * LDP + c] = Qg[c * NN + lane];
  __syncthreads();

  float acc[16];
  const int r0 = w * 16;
  #pragma unroll
  for (int i = 0; i < 16; ++i) acc[i] = 0.0f;
  for (int k = 0; k < NN; ++k) {
    float f = FF(k, lane);
    #pragma unroll
    for (int i = 0; i < 16; ++i) acc[i] += Qs[(r0 + i) * LDP + k] * f;
  }
  __syncthreads();
  float* W = Fp;
  #pragma unroll
  for (int i = 0; i < 16; ++i) W[(r0 + i) * LDP + lane] = acc[i];
  __syncthreads();

  #pragma unroll
  for (int i = 0; i < 16; ++i) acc[i] = 0.0f;
  for (int k = 0; k < NN; ++k) {
    float qv = Qs[lane * LDP + k];
    #pragma unroll
    for (int i = 0; i < 16; ++i) acc[i] += W[(r0 + i) * LDP + k] * qv;
  }
  #pragma unroll
  for (int i = 0; i < 16; ++i) dst[(r0 + i) * NN + lane] = acc[i];

  #undef TF
  #undef FF
}

extern "C" void kernel_launch(void* const* d_in, const int* in_sizes, int n_in,
                              void* d_out, int out_size, void* d_ws, size_t ws_size,
                              hipStream_t stream) {
  const float* x = (const float*)d_in[0];
  float* out = (float*)d_out;
  float* ws = (float*)d_ws;  // nmat*64*64*4 B = 64 MB dense T handoff
  const int nmat = in_sizes[0] / (NN * NN);  // 4096
  hess64_kernel<<<nmat, 64, 0, stream>>>(x, out, ws);
  qr64_kernel<<<nmat, 64, 0, stream>>>(out, ws);
  parlett64_kernel<<<nmat, 256, 0, stream>>>(ws, out);
}

// Round 10
// 6937.999 us; speedup vs baseline: 1.4045x; 1.0765x over previous
//
#include <hip/hip_runtime.h>

#define NN 64
#define LDP (NN + 1)  // +1 padding: kills the 32/64-way column-access bank conflicts

// Deflation tolerance: 1e-5 (R7-PROVEN; absmax 0.03125). R9 FAILED with 1e-4:
// Parlett's Sylvester solves divide by eigenvalue gaps (~0.01-0.1), so an
// erased subdiagonal of 1e-4*s (~6e-3) is amplified x10-100 in F -> 0.469.
// 1e-5 keeps the amplified error at ~0.06 worst-case, under the bf16 floor.
#define DEFL_TOL 1e-5

// Packed upper-Hessenberg band with 3 subdiagonals. Row r stores cols
// max(0,r-3)..63. 2266 floats = 9064 B.
#define BAND_SIZE 2266

__device__ __forceinline__ int rb_of(int r) {
  int t = (r >= 4) ? (((r - 4) * (r - 3)) >> 1) : 0;
  int s = (r >= 3) ? (r - 3) : 0;
  return 64 * r - t - s;
}

__device__ __forceinline__ double guard_d(double p) {
  if (fabs(p) < 1e-280) return (p >= 0.0) ? 1e-280 : -1e-280;
  return p;
}

// Wave-uniform lane read of a double via v_readlane (no LDS, no lgkmcnt).
__device__ __forceinline__ double readlane_d(double v, int l) {
  union { double d; int i[2]; } u;
  u.d = v;
  int a = __builtin_amdgcn_readlane(u.i[0], l);
  int b = __builtin_amdgcn_readlane(u.i[1], l);
  union { double d; int i[2]; } w;
  w.i[0] = a; w.i[1] = b;
  return w.d;
}

// R7-proven: NO explicit LDS fences in the single-wave kernels (one wave per
// block; LDS pipe processes a wave's DS ops in order; compiler preserves
// program order on potentially-aliasing __shared__ accesses). Global Q RMW
// still needs vmcnt ordering:
#define VM_FENCE()                                     \
  do {                                                 \
    asm volatile("s_waitcnt vmcnt(0)" ::: "memory");   \
    __builtin_amdgcn_sched_barrier(0);                 \
  } while (0)

// ============================================================================
// Kernel 1: Hessenberg reduction. NORMALIZED FLOAT reflector applies.
// H = I - u0*w*w^T with w=(1, x_1/v0, ..), |w_t|<=1, u0=|v0|/sg in [1,2] —
// bounded by construction, so float arithmetic cannot overflow/NaN (the
// R4/R5 hazard was UNnormalized float tau/v on tiny ||v||). Derivation
// (ss, sqrt, beta, iv0) stays double. The m-length dot/update loops (the
// entire cost of this kernel) run at f32 issue rate (2x f64).
// ============================================================================
__global__ __launch_bounds__(64) void hess64_kernel(const float* __restrict__ x,
                                                    float* __restrict__ out,
                                                    float* __restrict__ ws) {
  __shared__ float Td[NN][LDP];
  __shared__ float vbuf[NN];  // normalized w (|w|<=1), float

  const int lane = threadIdx.x;
  const size_t mat = blockIdx.x;
  const float* src = x + mat * NN * NN;
  float* Qg = out + mat * NN * NN;  // Q^T layout: Qg[c*64+r] = Q[r][c]
  float* Tg = ws + mat * NN * NN;

  for (int r = 0; r < NN; ++r) Td[r][lane] = src[r * NN + lane];
  for (int c = 0; c < NN; ++c) Qg[c * NN + lane] = (c == lane) ? 1.0f : 0.0f;

  for (int k = 0; k <= NN - 3; ++k) {
    const int m = NN - 1 - k;
    double xt = (lane < m) ? (double)Td[k + 1 + lane][k] : 0.0;
    double ss = xt * xt;
    #pragma unroll
    for (int off = 32; off; off >>= 1) ss += __shfl_xor(ss, off);
    double x0 = (double)Td[k + 1][k];
    if (ss > 1e-280) {  // uniform across wave
      double sg = sqrt(ss);
      double beta = (x0 >= 0.0) ? -sg : sg;
      double v0 = x0 - beta;            // |v0| = |x0| + sg >= sg > 0
      double iv0 = 1.0 / v0;
      const float u0f = (float)(fabs(v0) / sg);  // tau*v0^2, in [1,2]
      vbuf[lane] = (lane < m) ? (float)(((lane == 0) ? v0 : xt) * iv0) : 0.0f;
      if (lane >= k + 1) {  // left apply (FLOAT, normalized, bounded)
        const int j = lane;
        float acc = 0.0f;
        for (int t = 0; t < m; ++t) acc += vbuf[t] * Td[k + 1 + t][j];
        float fac = u0f * acc;
        for (int t = 0; t < m; ++t) Td[k + 1 + t][j] -= vbuf[t] * fac;
      }
      if (lane == 0) Td[k + 1][k] = (float)beta;
      if (lane >= 1 && lane < m) Td[k + 1 + lane][k] = 0.0f;
      VM_FENCE();  // Q RMW: iteration k-1's stores vs this iteration's loads
      {  // right apply on T (LDS) and Q (global, coalesced) — FLOAT
        const int r = lane;
        float acc = 0.0f, qa = 0.0f;
        for (int t = 0; t < m; ++t) {
          float wt = vbuf[t];
          acc += Td[r][k + 1 + t] * wt;
          qa += Qg[(k + 1 + t) * NN + r] * wt;
        }
        float facT = u0f * acc, facQ = u0f * qa;
        for (int t = 0; t < m; ++t) {
          float wt = vbuf[t];
          Td[r][k + 1 + t] -= facT * wt;
          Qg[(k + 1 + t) * NN + r] -= facQ * wt;
        }
      }
    }
  }

  for (int r = 0; r < NN; ++r) Tg[r * NN + lane] = Td[r][lane];
}

// ============================================================================
// Kernel 2: Francis double-shift QR on packed band. Split-precision:
//  - reflector derivation + RIGHT apply + handoff column: DOUBLE (the
//    convergence-critical chain — R4 proved float here fails);
//  - LEFT apply: FLOAT normalized (u0f,r1f,r2f bounded; its output passes
//    through float LDS storage anyway);
//  - deferred-Q apply: FLOAT (bounded rec values; Q orthogonal to ~1e-6).
// R7-kept: fence-free LDS, hoisted bases, chunked 16-deep Q prefetch,
// DEFL_TOL 1e-5.
// ============================================================================
#define TD(r, c) band[rb_of(r) + (c)]

__global__ __launch_bounds__(64) void qr64_kernel(float* __restrict__ out,
                                                  float* __restrict__ ws) {
  __shared__ float band[BAND_SIZE];
  __shared__ float recT[NN], recY[NN], recZ[NN];  // normalized reflector stash

  const int lane = threadIdx.x;
  const int myrb = rb_of(lane);                          // per-lane row base
  const int myrb_m1 = (lane >= 1) ? rb_of(lane - 1) : 0; // row above's base
  const size_t mat = blockIdx.x;
  float* Qg = out + mat * NN * NN;
  float* Tg = ws + mat * NN * NN;

  // dense H -> band
  for (int r = 0; r < NN; ++r) {
    int st = (r >= 3) ? (r - 3) : 0;
    if (lane >= st) band[rb_of(r) + lane] = Tg[r * NN + lane];
  }

  int hi = NN - 1;
  int its = 0, total = 0;
  while (hi > 0) {
    bool small = false;
    if (lane >= 1 && lane <= hi) {
      double s = fabs((double)band[myrb_m1 + lane - 1]) + fabs((double)band[myrb + lane]);
      if (s == 0.0) s = 1e-300;
      small = fabs((double)band[myrb + lane - 1]) <= DEFL_TOL * s;
    }
    unsigned long long msk = __ballot(small) | 1ULL;
    if (hi < 63) msk &= (2ULL << hi) - 1ULL;
    const int lo = 63 - __clzll(msk);
    if (lo > 0) {
      if (lane == 0) TD(lo, lo - 1) = 0.0f;
    }
    if (lo == hi) { hi -= 1; its = 0; continue; }
    if (lo == hi - 1) {  // 2x2 window (cold path, stays double)
      double a = TD(hi - 1, hi - 1), b = TD(hi - 1, hi);
      double c = TD(hi, hi - 1), d = TD(hi, hi);
      double pp = 0.5 * (a - d);
      double disc = pp * pp + b * c;
      if (disc >= 0.0) {  // real pair: rotate to triangular
        double sq = sqrt(disc);
        double mid = 0.5 * (a + d);
        double lam = mid + ((mid >= 0.0) ? sq : -sq);
        double u0 = b, u1 = lam - a;
        double w0 = lam - d, w1 = c;
        double nu = u0 * u0 + u1 * u1, nw = w0 * w0 + w1 * w1;
        double cs, sn;
        if (nu >= nw && nu > 1e-280) { double n2 = sqrt(nu); cs = u0 / n2; sn = u1 / n2; }
        else if (nw > 1e-280) { double n2 = sqrt(nw); cs = w0 / n2; sn = w1 / n2; }
        else { cs = 1.0; sn = 0.0; }
        {
          const int j = lane;
          const int jmin = (hi >= 2) ? (hi - 2) : 0;  // cols < hi-2 exact 0
          if (j >= jmin) {
            double r0 = TD(hi - 1, j), r1 = TD(hi, j);
            TD(hi - 1, j) = (float)(cs * r0 + sn * r1);
            TD(hi, j) = (float)(cs * r1 - sn * r0);
          }
        }
        {
          const int r = lane;
          if (r <= hi) {
            double c0 = TD(r, hi - 1), c1 = TD(r, hi);
            TD(r, hi - 1) = (float)(cs * c0 + sn * c1);
            TD(r, hi) = (float)(cs * c1 - sn * c0);
          }
        }
        VM_FENCE();  // drain prior deferred-Q stores before Q RMW
        {
          const int r = lane;
          double q0 = (double)Qg[(hi - 1) * NN + r], q1 = (double)Qg[hi * NN + r];
          Qg[(hi - 1) * NN + r] = (float)(cs * q0 + sn * q1);
          Qg[hi * NN + r] = (float)(cs * q1 - sn * q0);
        }
        if (lane == 0) TD(hi, hi - 1) = 0.0f;
      }
      hi -= 2; its = 0; continue;
    }
    ++its; ++total;
    if (its > 40 || total > 2000) {  // safety: force deflation
      if (lane == 0) TD(hi, hi - 1) = 0.0f;
      hi -= 1; its = 0; continue;
    }
    double sa, sb, sc2, sd2;
    if (its == 10 || its == 20 || its == 30) {  // exceptional shift
      double sx = fabs((double)TD(hi, hi - 1)) + fabs((double)TD(hi - 1, hi - 2));
      sa = 0.75 * sx + (double)TD(hi, hi); sb = -0.4375 * sx; sc2 = sx; sd2 = sa;
    } else {
      sa = TD(hi - 1, hi - 1); sb = TD(hi - 1, hi);
      sc2 = TD(hi, hi - 1); sd2 = TD(hi, hi);
    }
    double tr = sa + sd2;
    double det = sa * sd2 - sb * sc2;
    double h11 = TD(lo, lo), h12 = TD(lo, lo + 1), h21 = TD(lo + 1, lo);
    double h22 = TD(lo + 1, lo + 1), h32 = TD(lo + 2, lo + 1);
    double cvx = h11 * h11 + h12 * h21 - tr * h11 + det;
    double cvy = h21 * (h11 + h22 - tr);
    double cvz = h21 * h32;

    int nk = hi - lo;  // reflectors recorded this sweep (uniform register)
    for (int k = lo; k <= hi - 1; ++k) {  // bulge chase
      const int rbk = rb_of(k), rbk1 = rb_of(k + 1), rbk2 = rb_of(k + 2);
      const int nr = (k + 2 <= hi) ? 3 : 2;
      const double vx = cvx, vy = cvy, vz = (nr == 3) ? cvz : 0.0;
      double ss2 = vx * vx + vy * vy + vz * vz;
      if (ss2 < 1e-280) { nk = k - lo; break; }  // bulge collapsed
      double sg = sqrt(ss2);
      double beta = (vx >= 0.0) ? -sg : sg;
      double v0 = vx - beta, v1 = vy, v2 = vz;
      double tau = 1.0 / (ss2 - beta * vx);
      // normalized reflector (uniform, bounded: u0f in [1,2], |r*f| <= 1)
      double iv0 = 1.0 / v0;  // |v0| >= sg > 0 here
      const float u0f = (float)(tau * v0 * v0);
      const float r1f = (float)(v1 * iv0);
      const float r2f = (float)(v2 * iv0);
      if (lane == 0) { recT[k - lo] = u0f; recY[k - lo] = r1f; recZ[k - lo] = r2f; }
      const int jlo = (k > lo) ? k : lo;
      if (lane >= jlo) {  // left apply — FLOAT normalized (bounded)
        const int j = lane;
        float t0 = band[rbk + j], t1 = band[rbk1 + j];
        float t2v = (nr == 3) ? band[rbk2 + j] : 0.0f;
        float tt = u0f * (t0 + r1f * t1 + r2f * t2v);
        band[rbk + j] = t0 - tt;
        band[rbk1 + j] = t1 - r1f * tt;
        if (nr == 3) band[rbk2 + j] = t2v - r2f * tt;
      }
      if (lane == 0 && k > lo) {  // exact bulge zeros (col k-1)
        band[rbk + (k - 1)] = (float)beta;
        band[rbk1 + (k - 1)] = 0.0f;
        if (nr == 3) band[rbk2 + (k - 1)] = 0.0f;
      }
      const int rmax = (k + 3 <= hi) ? (k + 3) : hi;
      double n0 = 0.0, n1 = 0.0, n2 = 0.0;
      if (lane <= rmax) {  // right apply — DOUBLE (handoff chain, R5-proven)
        double c0 = band[myrb + k], c1 = band[myrb + k + 1];
        double c2v = (nr == 3) ? (double)band[myrb + k + 2] : 0.0;
        double tt = tau * (c0 * v0 + c1 * v1 + c2v * v2);
        n0 = c0 - tt * v0;
        n1 = c1 - tt * v1;
        n2 = c2v - tt * v2;
      }
      {  // register handoff of next bulge column (DOUBLE, never rounded)
        const int ly = (k + 2 <= 63) ? (k + 2) : 0;
        const int lz = (k + 3 <= hi) ? (k + 3) : 0;
        cvx = readlane_d(n0, k + 1);
        cvy = readlane_d(n0, ly);
        cvz = readlane_d(n0, lz);
      }
      if (lane <= rmax) {
        band[myrb + k] = (float)n0;
        band[myrb + k + 1] = (float)n1;
        if (nr == 3) band[myrb + k + 2] = (float)n2;
      }
    }

    // ---- deferred Q apply: chunked 16-deep prefetch, FLOAT (bounded) ----
    VM_FENCE();  // drain prior sweep's Q stores before reloading
    {
      float qw0 = Qg[lo * NN + lane];
      float qw1 = Qg[(lo + 1) * NN + lane];
      float qw2 = Qg[(lo + 2) * NN + lane];
      int done = 0;
      while (done < nk) {
        const int cnt = (nk - done < 16) ? (nk - done) : 16;
        float p[16];
        #pragma unroll
        for (int u = 0; u < 16; ++u) {  // issue all chunk loads together
          const int kc = lo + done + u + 3;
          p[u] = (u < cnt && kc <= hi) ? Qg[kc * NN + lane] : 0.0f;
        }
        #pragma unroll
        for (int u = 0; u < 16; ++u) {
          if (u < cnt) {
            const int i = done + u;
            const float u0 = recT[i], r1 = recY[i], r2 = recZ[i];
            const float t = u0 * (qw0 + r1 * qw1 + r2 * qw2);
            qw0 -= t;
            qw1 -= r1 * t;
            qw2 -= r2 * t;
            Qg[(lo + i) * NN + lane] = qw0;  // col lo+i final
            qw0 = qw1; qw1 = qw2; qw2 = p[u];
          }
        }
        done += 16;
      }
      if (nk == hi - lo) {
        Qg[hi * NN + lane] = qw0;  // flush last window col
      } else {  // collapsed at k = lo+nk: flush pending window cols
        const int k = lo + nk;
        Qg[k * NN + lane] = qw0;
        Qg[(k + 1) * NN + lane] = qw1;
        if (k + 2 <= hi) Qg[(k + 2) * NN + lane] = qw2;
      }
    }
  }

  // band -> dense Schur T (subdiag + upper only)
  for (int r = 0; r < NN; ++r) {
    float v = 0.0f;
    int st = (r >= 1) ? (r - 1) : 0;
    if (lane >= st) v = band[rb_of(r) + lane];
    Tg[r * NN + lane] = v;
  }
}

// ============================================================================
// Kernel 3: Parlett recurrence + symmetrize + Q Fs Q^T (R2-R7-proven,
// unchanged; multi-wave -> keeps __syncthreads).
// ============================================================================
__global__ __launch_bounds__(256) void parlett64_kernel(const float* __restrict__ ws,
                                                        float* __restrict__ out) {
  __shared__ float Tfbuf[NN * LDP];
  __shared__ float Fbuf[NN * LDP];
  __shared__ int blkstart[NN];
  __shared__ int bi_of[NN];
  float* Tf = Tfbuf;
  float* Fp = Fbuf;

  const int tid = threadIdx.x;
  const int w = tid >> 6;
  const int lane = tid & 63;
  const size_t mat = blockIdx.x;
  const float* Tg = ws + mat * NN * NN;
  float* dst = out + mat * NN * NN;
  float* Qg = dst;

  #define TF(r, c) ((double)Tf[(r) * LDP + (c)])
  #define FF(r, c) Fp[(r) * LDP + (c)]

  for (int r = w; r < NN; r += 4) Tf[r * LDP + lane] = Tg[r * NN + lane];
  __syncthreads();

  unsigned long long pair_mask =
      __ballot((lane < NN - 1) && (Tf[(lane + 1) * LDP + lane] != 0.0f));
  unsigned long long start_mask = ~(pair_mask << 1);
  const bool isstart = (start_mask >> lane) & 1ULL;
  const bool ispair = (pair_mask >> lane) & 1ULL;
  double fdiag = 0.0, mymod = 1e300;
  if (isstart) {
    if (ispair) {
      double a = TF(lane, lane), b = TF(lane, lane + 1);
      double c = TF(lane + 1, lane), d = TF(lane + 1, lane + 1);
      fdiag = sqrt(fmax(a * d - b * c, 0.0));
    } else {
      fdiag = fabs(TF(lane, lane));
    }
    mymod = fdiag;
  }
  #pragma unroll
  for (int off = 32; off; off >>= 1) mymod = fmin(mymod, __shfl_xor(mymod, off));
  const double cshift = 1e-6 * mymod;

  if (tid < NN) {
    int nb = (int)__popcll(start_mask & ((1ULL << lane) - 1ULL));
    bi_of[lane] = nb;
    if (isstart) blkstart[nb] = lane;
  }
  for (int r = w; r < NN; r += 4) FF(r, lane) = 0.0f;
  __syncthreads();
  if (tid < NN && isstart) {
    FF(lane, lane) = (float)fdiag;
    if (ispair) FF(lane + 1, lane + 1) = (float)fdiag;
  }
  __syncthreads();

  const int sub = lane & 3;
  const int si = (lane & ~3) | w;

  for (int dist = 1; dist < NN; ++dist) {
    const int sj = si + dist;
    bool active = (sj < NN) && ((start_mask >> si) & 1ULL) && ((start_mask >> sj) & 1ULL);
    if (active) {
      const int p = ((pair_mask >> si) & 1ULL) ? 2 : 1;
      const int q = ((pair_mask >> sj) & 1ULL) ? 2 : 1;
      const int bi0 = bi_of[si], bi1 = bi_of[sj];
      double c00 = 0, c01 = 0, c10 = 0, c11 = 0;
      for (int b = bi0 + sub; b < bi1; b += 4) {
        const int k = blkstart[b];
        const bool kp = (pair_mask >> k) & 1ULL;
        double f00 = FF(si, k);
        double f01 = kp ? (double)FF(si, k + 1) : 0.0;
        double f10 = (p == 2) ? (double)FF(si + 1, k) : 0.0;
        double f11 = (p == 2 && kp) ? (double)FF(si + 1, k + 1) : 0.0;
        double t00 = TF(k, sj);
        double t01 = (q == 2) ? TF(k, sj + 1) : 0.0;
        double t10 = kp ? TF(k + 1, sj) : 0.0;
        double t11 = (kp && q == 2) ? TF(k + 1, sj + 1) : 0.0;
        c00 += f00 * t00 + f01 * t10;
        c01 += f00 * t01 + f01 * t11;
        c10 += f10 * t00 + f11 * t10;
        c11 += f10 * t01 + f11 * t11;
      }
      for (int b = bi0 + 1 + sub; b <= bi1; b += 4) {
        const int k = blkstart[b];
        const bool kp = (pair_mask >> k) & 1ULL;
        double t00 = TF(si, k);
        double t01 = kp ? TF(si, k + 1) : 0.0;
        double t10 = (p == 2) ? TF(si + 1, k) : 0.0;
        double t11 = (p == 2 && kp) ? TF(si + 1, k + 1) : 0.0;
        double f00 = FF(k, sj);
        double f01 = (q == 2) ? (double)FF(k, sj + 1) : 0.0;
        double f10 = kp ? (double)FF(k + 1, sj) : 0.0;
        double f11 = (kp && q == 2) ? (double)FF(k + 1, sj + 1) : 0.0;
        c00 -= t00 * f00 + t01 * f10;
        c01 -= t00 * f01 + t01 * f11;
        c10 -= t10 * f00 + t11 * f10;
        c11 -= t10 * f01 + t11 * f11;
      }
      c00 += __shfl_xor(c00, 1); c00 += __shfl_xor(c00, 2);
      c01 += __shfl_xor(c01, 1); c01 += __shfl_xor(c01, 2);
      c10 += __shfl_xor(c10, 1); c10 += __shfl_xor(c10, 2);
      c11 += __shfl_xor(c11, 1); c11 += __shfl_xor(c11, 2);
      if (sub == 0) {
        double x00 = 0, x01 = 0, x10 = 0, x11 = 0;
        if (p == 1 && q == 1) {
          x00 = c00 / guard_d(TF(si, si) - TF(sj, sj));
        } else if (p == 2 && q == 1) {
          double t = TF(sj, sj);
          double m00 = TF(si, si) - t, m01 = TF(si, si + 1);
          double m10 = TF(si + 1, si), m11 = TF(si + 1, si + 1) - t;
          double dd = guard_d(m00 * m11 - m01 * m10);
          x00 = (m11 * c00 - m01 * c10) / dd;
          x10 = (m00 * c10 - m10 * c00) / dd;
        } else if (p == 1 && q == 2) {
          double t = TF(si, si);
          double m00 = t - TF(sj, sj), m01 = -TF(sj, sj + 1);
          double m10 = -TF(sj + 1, sj), m11 = t - TF(sj + 1, sj + 1);
          double dd = guard_d(m00 * m11 - m01 * m10);
          x00 = (c00 * m11 - c01 * m10) / dd;
          x01 = (c01 * m00 - c00 * m01) / dd;
        } else {
          double A00 = TF(si, si), A01 = TF(si, si + 1);
          double A10 = TF(si + 1, si), A11 = TF(si + 1, si + 1);
          double B00 = TF(sj, sj), B01 = TF(sj, sj + 1);
          double B10 = TF(sj + 1, sj), B11 = TF(sj + 1, sj + 1);
          double M[4][5] = {
              {A00 - B00, A01, -B10, 0.0, c00},
              {A10, A11 - B00, 0.0, -B10, c10},
              {-B01, 0.0, A00 - B11, A01, c01},
              {0.0, -B01, A10, A11 - B11, c11}};
          #pragma unroll
          for (int cc = 0; cc < 4; ++cc) {
            #pragma unroll
            for (int rr2 = cc + 1; rr2 < 4; ++rr2) {
              bool sw = fabs(M[rr2][cc]) > fabs(M[cc][cc]);
              #pragma unroll
              for (int t2 = cc; t2 < 5; ++t2) {
                double aa = M[cc][t2], bb = M[rr2][t2];
                M[cc][t2] = sw ? bb : aa;
                M[rr2][t2] = sw ? aa : bb;
              }
            }
            double inv = 1.0 / guard_d(M[cc][cc]);
            #pragma unroll
            for (int rr2 = cc + 1; rr2 < 4; ++rr2) {
              double f2 = M[rr2][cc] * inv;
              #pragma unroll
              for (int t2 = cc; t2 < 5; ++t2) M[rr2][t2] -= f2 * M[cc][t2];
            }
          }
          double z3 = M[3][4] / guard_d(M[3][3]);
          double z2 = (M[2][4] - M[2][3] * z3) / guard_d(M[2][2]);
          double z1 = (M[1][4] - M[1][3] * z3 - M[1][2] * z2) / guard_d(M[1][1]);
          double z0 = (M[0][4] - M[0][3] * z3 - M[0][2] * z2 - M[0][1] * z1) / guard_d(M[0][0]);
          x00 = z0; x10 = z1; x01 = z2; x11 = z3;
        }
        FF(si, sj) = (float)x00;
        if (q == 2) FF(si, sj + 1) = (float)x01;
        if (p == 2) {
          FF(si + 1, sj) = (float)x10;
          if (q == 2) FF(si + 1, sj + 1) = (float)x11;
        }
      }
    }
    __syncthreads();
  }

  {
    const int r = lane;
    for (int j = r + 1 + w; j < NN; j += 4) {
      float v = 0.5f * (FF(r, j) + FF(j, r));
      FF(r, j) = v;
      FF(j, r) = v;
    }
    if (w == 0) FF(r, r) += (float)cshift;
  }
  __syncthreads();

  float* Qs = Tf;  // T dead after Parlett
  for (int c = w; c < NN; c += 4) Qs[lane * LDP + c] = Qg[c * NN + lane];
  __syncthreads();

  float acc[16];
  const int r0 = w * 16;
  #pragma unroll
  for (int i = 0; i < 16; ++i) acc[i] = 0.0f;
  for (int k = 0; k < NN; ++k) {
    float f = FF(k, lane);
    #pragma unroll
    for (int i = 0; i < 16; ++i) acc[i] += Qs[(r0 + i) * LDP + k] * f;
  }
  __syncthreads();
  float* W = Fp;
  #pragma unroll
  for (int i = 0; i < 16; ++i) W[(r0 + i) * LDP + lane] = acc[i];
  __syncthreads();

  #pragma unroll
  for (int i = 0; i < 16; ++i) acc[i] = 0.0f;
  for (int k = 0; k < NN; ++k) {
    float qv = Qs[lane * LDP + k];
    #pragma unroll
    for (int i = 0; i < 16; ++i) acc[i] += W[(r0 + i) * LDP + k] * qv;
  }
  #pragma unroll
  for (int i = 0; i < 16; ++i) dst[(r0 + i) * NN + lane] = acc[i];

  #undef TF
  #undef FF
}

extern "C" void kernel_launch(void* const* d_in, const int* in_sizes, int n_in,
                              void* d_out, int out_size, void* d_ws, size_t ws_size,
                              hipStream_t stream) {
  const float* x = (const float*)d_in[0];
  float* out = (float*)d_out;
  float* ws = (float*)d_ws;  // nmat*64*64*4 B = 64 MB dense T handoff
  const int nmat = in_sizes[0] / (NN * NN);  // 4096
  hess64_kernel<<<nmat, 64, 0, stream>>>(x, out, ws);
  qr64_kernel<<<nmat, 64, 0, stream>>>(out, ws);
  parlett64_kernel<<<nmat, 256, 0, stream>>>(ws, out);
}

// Round 11
// 6933.873 us; speedup vs baseline: 1.4054x; 1.0006x over previous
//
#include <hip/hip_runtime.h>

#define NN 64
#define LDP (NN + 1)  // +1 padding: kills the 32/64-way column-access bank conflicts

// Deflation tolerance: 1e-5 (R7/R10-PROVEN; absmax 0.03125). R9 FAILED with
// 1e-4: Parlett's Sylvester solves divide by eigenvalue gaps (~0.01-0.1), so
// an erased subdiagonal of 1e-4*s is amplified x10-100 in F -> 0.469.
#define DEFL_TOL 1e-5

// Packed upper-Hessenberg band with 3 subdiagonals + PER-ROW BANK SKEW.
// Row r stores cols max(0,r-3)..63 at base rb_of(r). R11: skew sigma(r)
// added so every adjacent-row stride is ODD -> consecutive rows never share
// an LDS bank -> the right apply's 64-lane column access is the free 2-way
// minimum instead of 4+-way hotspots (R10: SQ_LDS_BANK_CONFLICT = 2.4e8,
// ~8% of CU-cycles; rows 0-3 had stride 64 = same bank).
// Max index rb_of(63)+63 = 2298 -> 2300 floats = 9200 B -> 16 blocks/CU.
#define BAND_SIZE 2300

__device__ __forceinline__ int rb_of(int r) {
  int t = (r >= 4) ? (((r - 4) * (r - 3)) >> 1) : 0;
  int s = (r >= 3) ? (r - 3) : 0;
  int sk = (r <= 3) ? r : 3 + ((r - 3) >> 1);  // makes all row strides odd
  return 64 * r - t - s + sk;
}

__device__ __forceinline__ double guard_d(double p) {
  if (fabs(p) < 1e-280) return (p >= 0.0) ? 1e-280 : -1e-280;
  return p;
}

// Wave-uniform lane read of a double via v_readlane (no LDS, no lgkmcnt).
__device__ __forceinline__ double readlane_d(double v, int l) {
  union { double d; int i[2]; } u;
  u.d = v;
  int a = __builtin_amdgcn_readlane(u.i[0], l);
  int b = __builtin_amdgcn_readlane(u.i[1], l);
  union { double d; int i[2]; } w;
  w.i[0] = a; w.i[1] = b;
  return w.d;
}

// R7-proven: NO explicit LDS fences in the single-wave kernels (one wave per
// block; LDS pipe processes a wave's DS ops in order; compiler preserves
// program order on potentially-aliasing __shared__ accesses). Global Q RMW
// still needs vmcnt ordering:
#define VM_FENCE()                                     \
  do {                                                 \
    asm volatile("s_waitcnt vmcnt(0)" ::: "memory");   \
    __builtin_amdgcn_sched_barrier(0);                 \
  } while (0)

// ============================================================================
// Kernel 1: Hessenberg reduction (R10-proven, unchanged). NORMALIZED FLOAT
// reflector applies (bounded: |w|<=1, u0 in [1,2]); derivation double.
// ============================================================================
__global__ __launch_bounds__(64) void hess64_kernel(const float* __restrict__ x,
                                                    float* __restrict__ out,
                                                    float* __restrict__ ws) {
  __shared__ float Td[NN][LDP];
  __shared__ float vbuf[NN];  // normalized w (|w|<=1), float

  const int lane = threadIdx.x;
  const size_t mat = blockIdx.x;
  const float* src = x + mat * NN * NN;
  float* Qg = out + mat * NN * NN;  // Q^T layout: Qg[c*64+r] = Q[r][c]
  float* Tg = ws + mat * NN * NN;

  for (int r = 0; r < NN; ++r) Td[r][lane] = src[r * NN + lane];
  for (int c = 0; c < NN; ++c) Qg[c * NN + lane] = (c == lane) ? 1.0f : 0.0f;

  for (int k = 0; k <= NN - 3; ++k) {
    const int m = NN - 1 - k;
    double xt = (lane < m) ? (double)Td[k + 1 + lane][k] : 0.0;
    double ss = xt * xt;
    #pragma unroll
    for (int off = 32; off; off >>= 1) ss += __shfl_xor(ss, off);
    double x0 = (double)Td[k + 1][k];
    if (ss > 1e-280) {  // uniform across wave
      double sg = sqrt(ss);
      double beta = (x0 >= 0.0) ? -sg : sg;
      double v0 = x0 - beta;            // |v0| = |x0| + sg >= sg > 0
      double iv0 = 1.0 / v0;
      const float u0f = (float)(fabs(v0) / sg);  // tau*v0^2, in [1,2]
      vbuf[lane] = (lane < m) ? (float)(((lane == 0) ? v0 : xt) * iv0) : 0.0f;
      if (lane >= k + 1) {  // left apply (FLOAT, normalized, bounded)
        const int j = lane;
        float acc = 0.0f;
        for (int t = 0; t < m; ++t) acc += vbuf[t] * Td[k + 1 + t][j];
        float fac = u0f * acc;
        for (int t = 0; t < m; ++t) Td[k + 1 + t][j] -= vbuf[t] * fac;
      }
      if (lane == 0) Td[k + 1][k] = (float)beta;
      if (lane >= 1 && lane < m) Td[k + 1 + lane][k] = 0.0f;
      VM_FENCE();  // Q RMW: iteration k-1's stores vs this iteration's loads
      {  // right apply on T (LDS) and Q (global, coalesced) — FLOAT
        const int r = lane;
        float acc = 0.0f, qa = 0.0f;
        for (int t = 0; t < m; ++t) {
          float wt = vbuf[t];
          acc += Td[r][k + 1 + t] * wt;
          qa += Qg[(k + 1 + t) * NN + r] * wt;
        }
        float facT = u0f * acc, facQ = u0f * qa;
        for (int t = 0; t < m; ++t) {
          float wt = vbuf[t];
          Td[r][k + 1 + t] -= facT * wt;
          Qg[(k + 1 + t) * NN + r] -= facQ * wt;
        }
      }
    }
  }

  for (int r = 0; r < NN; ++r) Tg[r * NN + lane] = Td[r][lane];
}

// ============================================================================
// Kernel 2: Francis double-shift QR on packed band (R10-proven split
// precision; R11 adds only the bank-skewed band layout — zero numeric delta).
//  - reflector derivation + RIGHT apply + handoff column: DOUBLE;
//  - LEFT apply + deferred-Q apply: FLOAT normalized (bounded);
//  - fence-free LDS, hoisted bases, chunked 16-deep Q prefetch, tol 1e-5.
// ============================================================================
#define TD(r, c) band[rb_of(r) + (c)]

__global__ __launch_bounds__(64) void qr64_kernel(float* __restrict__ out,
                                                  float* __restrict__ ws) {
  __shared__ float band[BAND_SIZE];
  __shared__ float recT[NN], recY[NN], recZ[NN];  // normalized reflector stash

  const int lane = threadIdx.x;
  const int myrb = rb_of(lane);                          // per-lane row base
  const int myrb_m1 = (lane >= 1) ? rb_of(lane - 1) : 0; // row above's base
  const size_t mat = blockIdx.x;
  float* Qg = out + mat * NN * NN;
  float* Tg = ws + mat * NN * NN;

  // dense H -> band
  for (int r = 0; r < NN; ++r) {
    int st = (r >= 3) ? (r - 3) : 0;
    if (lane >= st) band[rb_of(r) + lane] = Tg[r * NN + lane];
  }

  int hi = NN - 1;
  int its = 0, total = 0;
  while (hi > 0) {
    bool small = false;
    if (lane >= 1 && lane <= hi) {
      double s = fabs((double)band[myrb_m1 + lane - 1]) + fabs((double)band[myrb + lane]);
      if (s == 0.0) s = 1e-300;
      small = fabs((double)band[myrb + lane - 1]) <= DEFL_TOL * s;
    }
    unsigned long long msk = __ballot(small) | 1ULL;
    if (hi < 63) msk &= (2ULL << hi) - 1ULL;
    const int lo = 63 - __clzll(msk);
    if (lo > 0) {
      if (lane == 0) TD(lo, lo - 1) = 0.0f;
    }
    if (lo == hi) { hi -= 1; its = 0; continue; }
    if (lo == hi - 1) {  // 2x2 window (cold path, stays double)
      double a = TD(hi - 1, hi - 1), b = TD(hi - 1, hi);
      double c = TD(hi, hi - 1), d = TD(hi, hi);
      double pp = 0.5 * (a - d);
      double disc = pp * pp + b * c;
      if (disc >= 0.0) {  // real pair: rotate to triangular
        double sq = sqrt(disc);
        double mid = 0.5 * (a + d);
        double lam = mid + ((mid >= 0.0) ? sq : -sq);
        double u0 = b, u1 = lam - a;
        double w0 = lam - d, w1 = c;
        double nu = u0 * u0 + u1 * u1, nw = w0 * w0 + w1 * w1;
        double cs, sn;
        if (nu >= nw && nu > 1e-280) { double n2 = sqrt(nu); cs = u0 / n2; sn = u1 / n2; }
        else if (nw > 1e-280) { double n2 = sqrt(nw); cs = w0 / n2; sn = w1 / n2; }
        else { cs = 1.0; sn = 0.0; }
        {
          const int j = lane;
          const int jmin = (hi >= 2) ? (hi - 2) : 0;  // cols < hi-2 exact 0
          if (j >= jmin) {
            double r0 = TD(hi - 1, j), r1 = TD(hi, j);
            TD(hi - 1, j) = (float)(cs * r0 + sn * r1);
            TD(hi, j) = (float)(cs * r1 - sn * r0);
          }
        }
        {
          const int r = lane;
          if (r <= hi) {
            double c0 = TD(r, hi - 1), c1 = TD(r, hi);
            TD(r, hi - 1) = (float)(cs * c0 + sn * c1);
            TD(r, hi) = (float)(cs * c1 - sn * c0);
          }
        }
        VM_FENCE();  // drain prior deferred-Q stores before Q RMW
        {
          const int r = lane;
          double q0 = (double)Qg[(hi - 1) * NN + r], q1 = (double)Qg[hi * NN + r];
          Qg[(hi - 1) * NN + r] = (float)(cs * q0 + sn * q1);
          Qg[hi * NN + r] = (float)(cs * q1 - sn * q0);
        }
        if (lane == 0) TD(hi, hi - 1) = 0.0f;
      }
      hi -= 2; its = 0; continue;
    }
    ++its; ++total;
    if (its > 40 || total > 2000) {  // safety: force deflation
      if (lane == 0) TD(hi, hi - 1) = 0.0f;
      hi -= 1; its = 0; continue;
    }
    double sa, sb, sc2, sd2;
    if (its == 10 || its == 20 || its == 30) {  // exceptional shift
      double sx = fabs((double)TD(hi, hi - 1)) + fabs((double)TD(hi - 1, hi - 2));
      sa = 0.75 * sx + (double)TD(hi, hi); sb = -0.4375 * sx; sc2 = sx; sd2 = sa;
    } else {
      sa = TD(hi - 1, hi - 1); sb = TD(hi - 1, hi);
      sc2 = TD(hi, hi - 1); sd2 = TD(hi, hi);
    }
    double tr = sa + sd2;
    double det = sa * sd2 - sb * sc2;
    double h11 = TD(lo, lo), h12 = TD(lo, lo + 1), h21 = TD(lo + 1, lo);
    double h22 = TD(lo + 1, lo + 1), h32 = TD(lo + 2, lo + 1);
    double cvx = h11 * h11 + h12 * h21 - tr * h11 + det;
    double cvy = h21 * (h11 + h22 - tr);
    double cvz = h21 * h32;

    int nk = hi - lo;  // reflectors recorded this sweep (uniform register)
    for (int k = lo; k <= hi - 1; ++k) {  // bulge chase
      const int rbk = rb_of(k), rbk1 = rb_of(k + 1), rbk2 = rb_of(k + 2);
      const int nr = (k + 2 <= hi) ? 3 : 2;
      const double vx = cvx, vy = cvy, vz = (nr == 3) ? cvz : 0.0;
      double ss2 = vx * vx + vy * vy + vz * vz;
      if (ss2 < 1e-280) { nk = k - lo; break; }  // bulge collapsed
      double sg = sqrt(ss2);
      double beta = (vx >= 0.0) ? -sg : sg;
      double v0 = vx - beta, v1 = vy, v2 = vz;
      double tau = 1.0 / (ss2 - beta * vx);
      // normalized reflector (uniform, bounded: u0f in [1,2], |r*f| <= 1)
      double iv0 = 1.0 / v0;  // |v0| >= sg > 0 here
      const float u0f = (float)(tau * v0 * v0);
      const float r1f = (float)(v1 * iv0);
      const float r2f = (float)(v2 * iv0);
      if (lane == 0) { recT[k - lo] = u0f; recY[k - lo] = r1f; recZ[k - lo] = r2f; }
      const int jlo = (k > lo) ? k : lo;
      if (lane >= jlo) {  // left apply — FLOAT normalized (bounded)
        const int j = lane;
        float t0 = band[rbk + j], t1 = band[rbk1 + j];
        float t2v = (nr == 3) ? band[rbk2 + j] : 0.0f;
        float tt = u0f * (t0 + r1f * t1 + r2f * t2v);
        band[rbk + j] = t0 - tt;
        band[rbk1 + j] = t1 - r1f * tt;
        if (nr == 3) band[rbk2 + j] = t2v - r2f * tt;
      }
      if (lane == 0 && k > lo) {  // exact bulge zeros (col k-1)
        band[rbk + (k - 1)] = (float)beta;
        band[rbk1 + (k - 1)] = 0.0f;
        if (nr == 3) band[rbk2 + (k - 1)] = 0.0f;
      }
      const int rmax = (k + 3 <= hi) ? (k + 3) : hi;
      double n0 = 0.0, n1 = 0.0, n2 = 0.0;
      if (lane <= rmax) {  // right apply — DOUBLE (handoff chain, R5-proven)
        double c0 = band[myrb + k], c1 = band[myrb + k + 1];
        double c2v = (nr == 3) ? (double)band[myrb + k + 2] : 0.0;
        double tt = tau * (c0 * v0 + c1 * v1 + c2v * v2);
        n0 = c0 - tt * v0;
        n1 = c1 - tt * v1;
        n2 = c2v - tt * v2;
      }
      {  // register handoff of next bulge column (DOUBLE, never rounded)
        const int ly = (k + 2 <= 63) ? (k + 2) : 0;
        const int lz = (k + 3 <= hi) ? (k + 3) : 0;
        cvx = readlane_d(n0, k + 1);
        cvy = readlane_d(n0, ly);
        cvz = readlane_d(n0, lz);
      }
      if (lane <= rmax) {
        band[myrb + k] = (float)n0;
        band[myrb + k + 1] = (float)n1;
        if (nr == 3) band[myrb + k + 2] = (float)n2;
      }
    }

    // ---- deferred Q apply: chunked 16-deep prefetch, FLOAT (bounded) ----
    VM_FENCE();  // drain prior sweep's Q stores before reloading
    {
      float qw0 = Qg[lo * NN + lane];
      float qw1 = Qg[(lo + 1) * NN + lane];
      float qw2 = Qg[(lo + 2) * NN + lane];
      int done = 0;
      while (done < nk) {
        const int cnt = (nk - done < 16) ? (nk - done) : 16;
        float p[16];
        #pragma unroll
        for (int u = 0; u < 16; ++u) {  // issue all chunk loads together
          const int kc = lo + done + u + 3;
          p[u] = (u < cnt && kc <= hi) ? Qg[kc * NN + lane] : 0.0f;
        }
        #pragma unroll
        for (int u = 0; u < 16; ++u) {
          if (u < cnt) {
            const int i = done + u;
            const float u0 = recT[i], r1 = recY[i], r2 = recZ[i];
            const float t = u0 * (qw0 + r1 * qw1 + r2 * qw2);
            qw0 -= t;
            qw1 -= r1 * t;
            qw2 -= r2 * t;
            Qg[(lo + i) * NN + lane] = qw0;  // col lo+i final
            qw0 = qw1; qw1 = qw2; qw2 = p[u];
          }
        }
        done += 16;
      }
      if (nk == hi - lo) {
        Qg[hi * NN + lane] = qw0;  // flush last window col
      } else {  // collapsed at k = lo+nk: flush pending window cols
        const int k = lo + nk;
        Qg[k * NN + lane] = qw0;
        Qg[(k + 1) * NN + lane] = qw1;
        if (k + 2 <= hi) Qg[(k + 2) * NN + lane] = qw2;
      }
    }
  }

  // band -> dense Schur T (subdiag + upper only)
  for (int r = 0; r < NN; ++r) {
    float v = 0.0f;
    int st = (r >= 1) ? (r - 1) : 0;
    if (lane >= st) v = band[rb_of(r) + lane];
    Tg[r * NN + lane] = v;
  }
}

// ============================================================================
// Kernel 3: Parlett recurrence + symmetrize + Q Fs Q^T. R11: the two k-sum
// dot loops accumulate in FLOAT (F,T are float storage already; relative
// error ~1e-7 enters before the 1/gap amplification at the same point the
// proven-safe 1e-5 tol noise does — 100x smaller). Sylvester solves stay
// DOUBLE. Halves the dominant f64 issue + cheapens the shfl reduces.
// ============================================================================
__global__ __launch_bounds__(256) void parlett64_kernel(const float* __restrict__ ws,
                                                        float* __restrict__ out) {
  __shared__ float Tfbuf[NN * LDP];
  __shared__ float Fbuf[NN * LDP];
  __shared__ int blkstart[NN];
  __shared__ int bi_of[NN];
  float* Tf = Tfbuf;
  float* Fp = Fbuf;

  const int tid = threadIdx.x;
  const int w = tid >> 6;
  const int lane = tid & 63;
  const size_t mat = blockIdx.x;
  const float* Tg = ws + mat * NN * NN;
  float* dst = out + mat * NN * NN;
  float* Qg = dst;

  #define TF(r, c) ((double)Tf[(r) * LDP + (c)])
  #define TFF(r, c) Tf[(r) * LDP + (c)]
  #define FF(r, c) Fp[(r) * LDP + (c)]

  for (int r = w; r < NN; r += 4) Tf[r * LDP + lane] = Tg[r * NN + lane];
  __syncthreads();

  unsigned long long pair_mask =
      __ballot((lane < NN - 1) && (Tf[(lane + 1) * LDP + lane] != 0.0f));
  unsigned long long start_mask = ~(pair_mask << 1);
  const bool isstart = (start_mask >> lane) & 1ULL;
  const bool ispair = (pair_mask >> lane) & 1ULL;
  double fdiag = 0.0, mymod = 1e300;
  if (isstart) {
    if (ispair) {
      double a = TF(lane, lane), b = TF(lane, lane + 1);
      double c = TF(lane + 1, lane), d = TF(lane + 1, lane + 1);
      fdiag = sqrt(fmax(a * d - b * c, 0.0));
    } else {
      fdiag = fabs(TF(lane, lane));
    }
    mymod = fdiag;
  }
  #pragma unroll
  for (int off = 32; off; off >>= 1) mymod = fmin(mymod, __shfl_xor(mymod, off));
  const double cshift = 1e-6 * mymod;

  if (tid < NN) {
    int nb = (int)__popcll(start_mask & ((1ULL << lane) - 1ULL));
    bi_of[lane] = nb;
    if (isstart) blkstart[nb] = lane;
  }
  for (int r = w; r < NN; r += 4) FF(r, lane) = 0.0f;
  __syncthreads();
  if (tid < NN && isstart) {
    FF(lane, lane) = (float)fdiag;
    if (ispair) FF(lane + 1, lane + 1) = (float)fdiag;
  }
  __syncthreads();

  const int sub = lane & 3;
  const int si = (lane & ~3) | w;

  for (int dist = 1; dist < NN; ++dist) {
    const int sj = si + dist;
    bool active = (sj < NN) && ((start_mask >> si) & 1ULL) && ((start_mask >> sj) & 1ULL);
    if (active) {
      const int p = ((pair_mask >> si) & 1ULL) ? 2 : 1;
      const int q = ((pair_mask >> sj) & 1ULL) ? 2 : 1;
      const int bi0 = bi_of[si], bi1 = bi_of[sj];
      float c00 = 0, c01 = 0, c10 = 0, c11 = 0;  // FLOAT accumulation (R11)
      for (int b = bi0 + sub; b < bi1; b += 4) {
        const int k = blkstart[b];
        const bool kp = (pair_mask >> k) & 1ULL;
        float f00 = FF(si, k);
        float f01 = kp ? FF(si, k + 1) : 0.0f;
        float f10 = (p == 2) ? FF(si + 1, k) : 0.0f;
        float f11 = (p == 2 && kp) ? FF(si + 1, k + 1) : 0.0f;
        float t00 = TFF(k, sj);
        float t01 = (q == 2) ? TFF(k, sj + 1) : 0.0f;
        float t10 = kp ? TFF(k + 1, sj) : 0.0f;
        float t11 = (kp && q == 2) ? TFF(k + 1, sj + 1) : 0.0f;
        c00 += f00 * t00 + f01 * t10;
        c01 += f00 * t01 + f01 * t11;
        c10 += f10 * t00 + f11 * t10;
        c11 += f10 * t01 + f11 * t11;
      }
      for (int b = bi0 + 1 + sub; b <= bi1; b += 4) {
        const int k = blkstart[b];
        const bool kp = (pair_mask >> k) & 1ULL;
        float t00 = TFF(si, k);
        float t01 = kp ? TFF(si, k + 1) : 0.0f;
        float t10 = (p == 2) ? TFF(si + 1, k) : 0.0f;
        float t11 = (p == 2 && kp) ? TFF(si + 1, k + 1) : 0.0f;
        float f00 = FF(k, sj);
        float f01 = (q == 2) ? FF(k, sj + 1) : 0.0f;
        float f10 = kp ? FF(k + 1, sj) : 0.0f;
        float f11 = (kp && q == 2) ? FF(k + 1, sj + 1) : 0.0f;
        c00 -= t00 * f00 + t01 * f10;
        c01 -= t00 * f01 + t01 * f11;
        c10 -= t10 * f00 + t11 * f10;
        c11 -= t10 * f01 + t11 * f11;
      }
      c00 += __shfl_xor(c00, 1); c00 += __shfl_xor(c00, 2);
      c01 += __shfl_xor(c01, 1); c01 += __shfl_xor(c01, 2);
      c10 += __shfl_xor(c10, 1); c10 += __shfl_xor(c10, 2);
      c11 += __shfl_xor(c11, 1); c11 += __shfl_xor(c11, 2);
      if (sub == 0) {
        // solves in DOUBLE (gap-division: the R9-failure amplification point)
        double d00 = (double)c00, d01 = (double)c01;
        double d10 = (double)c10, d11 = (double)c11;
        double x00 = 0, x01 = 0, x10 = 0, x11 = 0;
        if (p == 1 && q == 1) {
          x00 = d00 / guard_d(TF(si, si) - TF(sj, sj));
        } else if (p == 2 && q == 1) {
          double t = TF(sj, sj);
          double m00 = TF(si, si) - t, m01 = TF(si, si + 1);
          double m10 = TF(si + 1, si), m11 = TF(si + 1, si + 1) - t;
          double dd = guard_d(m00 * m11 - m01 * m10);
          x00 = (m11 * d00 - m01 * d10) / dd;
          x10 = (m00 * d10 - m10 * d00) / dd;
        } else if (p == 1 && q == 2) {
          double t = TF(si, si);
          double m00 = t - TF(sj, sj), m01 = -TF(sj, sj + 1);
          double m10 = -TF(sj + 1, sj), m11 = t - TF(sj + 1, sj + 1);
          double dd = guard_d(m00 * m11 - m01 * m10);
          x00 = (d00 * m11 - d01 * m10) / dd;
          x01 = (d01 * m00 - d00 * m01) / dd;
        } else {
          double A00 = TF(si, si), A01 = TF(si, si + 1);
          double A10 = TF(si + 1, si), A11 = TF(si + 1, si + 1);
          double B00 = TF(sj, sj), B01 = TF(sj, sj + 1);
          double B10 = TF(sj + 1, sj), B11 = TF(sj + 1, sj + 1);
          double M[4][5] = {
              {A00 - B00, A01, -B10, 0.0, d00},
              {A10, A11 - B00, 0.0, -B10, d10},
              {-B01, 0.0, A00 - B11, A01, d01},
              {0.0, -B01, A10, A11 - B11, d11}};
          #pragma unroll
          for (int cc = 0; cc < 4; ++cc) {
            #pragma unroll
            for (int rr2 = cc + 1; rr2 < 4; ++rr2) {
              bool sw = fabs(M[rr2][cc]) > fabs(M[cc][cc]);
              #pragma unroll
              for (int t2 = cc; t2 < 5; ++t2) {
                double aa = M[cc][t2], bb = M[rr2][t2];
                M[cc][t2] = sw ? bb : aa;
                M[rr2][t2] = sw ? aa : bb;
              }
            }
            double inv = 1.0 / guard_d(M[cc][cc]);
            #pragma unroll
            for (int rr2 = cc + 1; rr2 < 4; ++rr2) {
              double f2 = M[rr2][cc] * inv;
              #pragma unroll
              for (int t2 = cc; t2 < 5; ++t2) M[rr2][t2] -= f2 * M[cc][t2];
            }
          }
          double z3 = M[3][4] / guard_d(M[3][3]);
          double z2 = (M[2][4] - M[2][3] * z3) / guard_d(M[2][2]);
          double z1 = (M[1][4] - M[1][3] * z3 - M[1][2] * z2) / guard_d(M[1][1]);
          double z0 = (M[0][4] - M[0][3] * z3 - M[0][2] * z2 - M[0][1] * z1) / guard_d(M[0][0]);
          x00 = z0; x10 = z1; x01 = z2; x11 = z3;
        }
        FF(si, sj) = (float)x00;
        if (q == 2) FF(si, sj + 1) = (float)x01;
        if (p == 2) {
          FF(si + 1, sj) = (float)x10;
          if (q == 2) FF(si + 1, sj + 1) = (float)x11;
        }
      }
    }
    __syncthreads();
  }

  {
    const int r = lane;
    for (int j = r + 1 + w; j < NN; j += 4) {
      float v = 0.5f * (FF(r, j) + FF(j, r));
      FF(r, j) = v;
      FF(j, r) = v;
    }
    if (w == 0) FF(r, r) += (float)cshift;
  }
  __syncthreads();

  float* Qs = Tf;  // T dead after Parlett
  for (int c = w; c < NN; c += 4) Qs[lane * LDP + c] = Qg[c * NN + lane];
  __syncthreads();

  float acc[16];
  const int r0 = w * 16;
  #pragma unroll
  for (int i = 0; i < 16; ++i) acc[i] = 0.0f;
  for (int k = 0; k < NN; ++k) {
    float f = FF(k, lane);
    #pragma unroll
    for (int i = 0; i < 16; ++i) acc[i] += Qs[(r0 + i) * LDP + k] * f;
  }
  __syncthreads();
  float* W = Fp;
  #pragma unroll
  for (int i = 0; i < 16; ++i) W[(r0 + i) * LDP + lane] = acc[i];
  __syncthreads();

  #pragma unroll
  for (int i = 0; i < 16; ++i) acc[i] = 0.0f;
  for (int k = 0; k < NN; ++k) {
    float qv = Qs[lane * LDP + k];
    #pragma unroll
    for (int i = 0; i < 16; ++i) acc[i] += W[(r0 + i) * LDP + k] * qv;
  }
  #pragma unroll
  for (int i = 0; i < 16; ++i) dst[(r0 + i) * NN + lane] = acc[i];

  #undef TF
  #undef TFF
  #undef FF
}

extern "C" void kernel_launch(void* const* d_in, const int* in_sizes, int n_in,
                              void* d_out, int out_size, void* d_ws, size_t ws_size,
                              hipStream_t stream) {
  const float* x = (const float*)d_in[0];
  float* out = (float*)d_out;
  float* ws = (float*)d_ws;  // nmat*64*64*4 B = 64 MB dense T handoff
  const int nmat = in_sizes[0] / (NN * NN);  // 4096
  hess64_kernel<<<nmat, 64, 0, stream>>>(x, out, ws);
  qr64_kernel<<<nmat, 64, 0, stream>>>(out, ws);
  parlett64_kernel<<<nmat, 256, 0, stream>>>(ws, out);
}

// Round 12
// 6368.073 us; speedup vs baseline: 1.5302x; 1.0888x over previous
//
#include <hip/hip_runtime.h>

#define NN 64
#define LDP (NN + 1)  // +1 padding: kills the 32/64-way column-access bank conflicts

// Deflation tolerance: 1e-5 (R7/R10-PROVEN; absmax 0.03125). R9 FAILED with
// 1e-4: Parlett's Sylvester solves divide by eigenvalue gaps (~0.01-0.1), so
// an erased subdiagonal of 1e-4*s is amplified x10-100 in F -> 0.469.
#define DEFL_TOL 1e-5

// Packed upper-Hessenberg band with 3 subdiagonals (R10-PROVEN layout).
// Row r stores cols max(0,r-3)..63. 2266 floats = 9064 B -> 16 blocks/CU.
// R11's odd-stride skew REVERTED: it cut conflicts only 20% (wrong conflict-
// source model) while adding VALU to the serial chain -> qr64 +9%.
#define BAND_SIZE 2266

__device__ __forceinline__ int rb_of(int r) {
  int t = (r >= 4) ? (((r - 4) * (r - 3)) >> 1) : 0;
  int s = (r >= 3) ? (r - 3) : 0;
  return 64 * r - t - s;
}

__device__ __forceinline__ double guard_d(double p) {
  if (fabs(p) < 1e-280) return (p >= 0.0) ? 1e-280 : -1e-280;
  return p;
}

// Wave-uniform lane read of a double via v_readlane (no LDS, no lgkmcnt).
__device__ __forceinline__ double readlane_d(double v, int l) {
  union { double d; int i[2]; } u;
  u.d = v;
  int a = __builtin_amdgcn_readlane(u.i[0], l);
  int b = __builtin_amdgcn_readlane(u.i[1], l);
  union { double d; int i[2]; } w;
  w.i[0] = a; w.i[1] = b;
  return w.d;
}

// R7-proven: NO explicit LDS fences in the single-wave kernels (one wave per
// block; LDS pipe processes a wave's DS ops in order; compiler preserves
// program order on potentially-aliasing __shared__ accesses). Global Q RMW
// still needs vmcnt ordering:
#define VM_FENCE()                                     \
  do {                                                 \
    asm volatile("s_waitcnt vmcnt(0)" ::: "memory");   \
    __builtin_amdgcn_sched_barrier(0);                 \
  } while (0)

// ============================================================================
// Kernel 1: Hessenberg reduction (R10-proven, unchanged). NORMALIZED FLOAT
// reflector applies (bounded: |w|<=1, u0 in [1,2]); derivation double.
// ============================================================================
__global__ __launch_bounds__(64) void hess64_kernel(const float* __restrict__ x,
                                                    float* __restrict__ out,
                                                    float* __restrict__ ws) {
  __shared__ float Td[NN][LDP];
  __shared__ float vbuf[NN];  // normalized w (|w|<=1), float

  const int lane = threadIdx.x;
  const size_t mat = blockIdx.x;
  const float* src = x + mat * NN * NN;
  float* Qg = out + mat * NN * NN;  // Q^T layout: Qg[c*64+r] = Q[r][c]
  float* Tg = ws + mat * NN * NN;

  for (int r = 0; r < NN; ++r) Td[r][lane] = src[r * NN + lane];
  for (int c = 0; c < NN; ++c) Qg[c * NN + lane] = (c == lane) ? 1.0f : 0.0f;

  for (int k = 0; k <= NN - 3; ++k) {
    const int m = NN - 1 - k;
    double xt = (lane < m) ? (double)Td[k + 1 + lane][k] : 0.0;
    double ss = xt * xt;
    #pragma unroll
    for (int off = 32; off; off >>= 1) ss += __shfl_xor(ss, off);
    double x0 = (double)Td[k + 1][k];
    if (ss > 1e-280) {  // uniform across wave
      double sg = sqrt(ss);
      double beta = (x0 >= 0.0) ? -sg : sg;
      double v0 = x0 - beta;            // |v0| = |x0| + sg >= sg > 0
      double iv0 = 1.0 / v0;
      const float u0f = (float)(fabs(v0) / sg);  // tau*v0^2, in [1,2]
      vbuf[lane] = (lane < m) ? (float)(((lane == 0) ? v0 : xt) * iv0) : 0.0f;
      if (lane >= k + 1) {  // left apply (FLOAT, normalized, bounded)
        const int j = lane;
        float acc = 0.0f;
        for (int t = 0; t < m; ++t) acc += vbuf[t] * Td[k + 1 + t][j];
        float fac = u0f * acc;
        for (int t = 0; t < m; ++t) Td[k + 1 + t][j] -= vbuf[t] * fac;
      }
      if (lane == 0) Td[k + 1][k] = (float)beta;
      if (lane >= 1 && lane < m) Td[k + 1 + lane][k] = 0.0f;
      VM_FENCE();  // Q RMW: iteration k-1's stores vs this iteration's loads
      {  // right apply on T (LDS) and Q (global, coalesced) — FLOAT
        const int r = lane;
        float acc = 0.0f, qa = 0.0f;
        for (int t = 0; t < m; ++t) {
          float wt = vbuf[t];
          acc += Td[r][k + 1 + t] * wt;
          qa += Qg[(k + 1 + t) * NN + r] * wt;
        }
        float facT = u0f * acc, facQ = u0f * qa;
        for (int t = 0; t < m; ++t) {
          float wt = vbuf[t];
          Td[r][k + 1 + t] -= facT * wt;
          Qg[(k + 1 + t) * NN + r] -= facQ * wt;
        }
      }
    }
  }

  for (int r = 0; r < NN; ++r) Tg[r * NN + lane] = Td[r][lane];
}

// ============================================================================
// Kernel 2: Francis double-shift QR on packed band (R10-proven, unchanged —
// R11's skew reverted).
//  - reflector derivation + RIGHT apply + handoff column: DOUBLE;
//  - LEFT apply + deferred-Q apply: FLOAT normalized (bounded);
//  - fence-free LDS, hoisted bases, chunked 16-deep Q prefetch, tol 1e-5.
// ============================================================================
#define TD(r, c) band[rb_of(r) + (c)]

__global__ __launch_bounds__(64) void qr64_kernel(float* __restrict__ out,
                                                  float* __restrict__ ws) {
  __shared__ float band[BAND_SIZE];
  __shared__ float recT[NN], recY[NN], recZ[NN];  // normalized reflector stash

  const int lane = threadIdx.x;
  const int myrb = rb_of(lane);                          // per-lane row base
  const int myrb_m1 = (lane >= 1) ? rb_of(lane - 1) : 0; // row above's base
  const size_t mat = blockIdx.x;
  float* Qg = out + mat * NN * NN;
  float* Tg = ws + mat * NN * NN;

  // dense H -> band
  for (int r = 0; r < NN; ++r) {
    int st = (r >= 3) ? (r - 3) : 0;
    if (lane >= st) band[rb_of(r) + lane] = Tg[r * NN + lane];
  }

  int hi = NN - 1;
  int its = 0, total = 0;
  while (hi > 0) {
    bool small = false;
    if (lane >= 1 && lane <= hi) {
      double s = fabs((double)band[myrb_m1 + lane - 1]) + fabs((double)band[myrb + lane]);
      if (s == 0.0) s = 1e-300;
      small = fabs((double)band[myrb + lane - 1]) <= DEFL_TOL * s;
    }
    unsigned long long msk = __ballot(small) | 1ULL;
    if (hi < 63) msk &= (2ULL << hi) - 1ULL;
    const int lo = 63 - __clzll(msk);
    if (lo > 0) {
      if (lane == 0) TD(lo, lo - 1) = 0.0f;
    }
    if (lo == hi) { hi -= 1; its = 0; continue; }
    if (lo == hi - 1) {  // 2x2 window (cold path, stays double)
      double a = TD(hi - 1, hi - 1), b = TD(hi - 1, hi);
      double c = TD(hi, hi - 1), d = TD(hi, hi);
      double pp = 0.5 * (a - d);
      double disc = pp * pp + b * c;
      if (disc >= 0.0) {  // real pair: rotate to triangular
        double sq = sqrt(disc);
        double mid = 0.5 * (a + d);
        double lam = mid + ((mid >= 0.0) ? sq : -sq);
        double u0 = b, u1 = lam - a;
        double w0 = lam - d, w1 = c;
        double nu = u0 * u0 + u1 * u1, nw = w0 * w0 + w1 * w1;
        double cs, sn;
        if (nu >= nw && nu > 1e-280) { double n2 = sqrt(nu); cs = u0 / n2; sn = u1 / n2; }
        else if (nw > 1e-280) { double n2 = sqrt(nw); cs = w0 / n2; sn = w1 / n2; }
        else { cs = 1.0; sn = 0.0; }
        {
          const int j = lane;
          const int jmin = (hi >= 2) ? (hi - 2) : 0;  // cols < hi-2 exact 0
          if (j >= jmin) {
            double r0 = TD(hi - 1, j), r1 = TD(hi, j);
            TD(hi - 1, j) = (float)(cs * r0 + sn * r1);
            TD(hi, j) = (float)(cs * r1 - sn * r0);
          }
        }
        {
          const int r = lane;
          if (r <= hi) {
            double c0 = TD(r, hi - 1), c1 = TD(r, hi);
            TD(r, hi - 1) = (float)(cs * c0 + sn * c1);
            TD(r, hi) = (float)(cs * c1 - sn * c0);
          }
        }
        VM_FENCE();  // drain prior deferred-Q stores before Q RMW
        {
          const int r = lane;
          double q0 = (double)Qg[(hi - 1) * NN + r], q1 = (double)Qg[hi * NN + r];
          Qg[(hi - 1) * NN + r] = (float)(cs * q0 + sn * q1);
          Qg[hi * NN + r] = (float)(cs * q1 - sn * q0);
        }
        if (lane == 0) TD(hi, hi - 1) = 0.0f;
      }
      hi -= 2; its = 0; continue;
    }
    ++its; ++total;
    if (its > 40 || total > 2000) {  // safety: force deflation
      if (lane == 0) TD(hi, hi - 1) = 0.0f;
      hi -= 1; its = 0; continue;
    }
    double sa, sb, sc2, sd2;
    if (its == 10 || its == 20 || its == 30) {  // exceptional shift
      double sx = fabs((double)TD(hi, hi - 1)) + fabs((double)TD(hi - 1, hi - 2));
      sa = 0.75 * sx + (double)TD(hi, hi); sb = -0.4375 * sx; sc2 = sx; sd2 = sa;
    } else {
      sa = TD(hi - 1, hi - 1); sb = TD(hi - 1, hi);
      sc2 = TD(hi, hi - 1); sd2 = TD(hi, hi);
    }
    double tr = sa + sd2;
    double det = sa * sd2 - sb * sc2;
    double h11 = TD(lo, lo), h12 = TD(lo, lo + 1), h21 = TD(lo + 1, lo);
    double h22 = TD(lo + 1, lo + 1), h32 = TD(lo + 2, lo + 1);
    double cvx = h11 * h11 + h12 * h21 - tr * h11 + det;
    double cvy = h21 * (h11 + h22 - tr);
    double cvz = h21 * h32;

    int nk = hi - lo;  // reflectors recorded this sweep (uniform register)
    for (int k = lo; k <= hi - 1; ++k) {  // bulge chase
      const int rbk = rb_of(k), rbk1 = rb_of(k + 1), rbk2 = rb_of(k + 2);
      const int nr = (k + 2 <= hi) ? 3 : 2;
      const double vx = cvx, vy = cvy, vz = (nr == 3) ? cvz : 0.0;
      double ss2 = vx * vx + vy * vy + vz * vz;
      if (ss2 < 1e-280) { nk = k - lo; break; }  // bulge collapsed
      double sg = sqrt(ss2);
      double beta = (vx >= 0.0) ? -sg : sg;
      double v0 = vx - beta, v1 = vy, v2 = vz;
      double tau = 1.0 / (ss2 - beta * vx);
      // normalized reflector (uniform, bounded: u0f in [1,2], |r*f| <= 1)
      double iv0 = 1.0 / v0;  // |v0| >= sg > 0 here
      const float u0f = (float)(tau * v0 * v0);
      const float r1f = (float)(v1 * iv0);
      const float r2f = (float)(v2 * iv0);
      if (lane == 0) { recT[k - lo] = u0f; recY[k - lo] = r1f; recZ[k - lo] = r2f; }
      const int jlo = (k > lo) ? k : lo;
      if (lane >= jlo) {  // left apply — FLOAT normalized (bounded)
        const int j = lane;
        float t0 = band[rbk + j], t1 = band[rbk1 + j];
        float t2v = (nr == 3) ? band[rbk2 + j] : 0.0f;
        float tt = u0f * (t0 + r1f * t1 + r2f * t2v);
        band[rbk + j] = t0 - tt;
        band[rbk1 + j] = t1 - r1f * tt;
        if (nr == 3) band[rbk2 + j] = t2v - r2f * tt;
      }
      if (lane == 0 && k > lo) {  // exact bulge zeros (col k-1)
        band[rbk + (k - 1)] = (float)beta;
        band[rbk1 + (k - 1)] = 0.0f;
        if (nr == 3) band[rbk2 + (k - 1)] = 0.0f;
      }
      const int rmax = (k + 3 <= hi) ? (k + 3) : hi;
      double n0 = 0.0, n1 = 0.0, n2 = 0.0;
      if (lane <= rmax) {  // right apply — DOUBLE (handoff chain, R5-proven)
        double c0 = band[myrb + k], c1 = band[myrb + k + 1];
        double c2v = (nr == 3) ? (double)band[myrb + k + 2] : 0.0;
        double tt = tau * (c0 * v0 + c1 * v1 + c2v * v2);
        n0 = c0 - tt * v0;
        n1 = c1 - tt * v1;
        n2 = c2v - tt * v2;
      }
      {  // register handoff of next bulge column (DOUBLE, never rounded)
        const int ly = (k + 2 <= 63) ? (k + 2) : 0;
        const int lz = (k + 3 <= hi) ? (k + 3) : 0;
        cvx = readlane_d(n0, k + 1);
        cvy = readlane_d(n0, ly);
        cvz = readlane_d(n0, lz);
      }
      if (lane <= rmax) {
        band[myrb + k] = (float)n0;
        band[myrb + k + 1] = (float)n1;
        if (nr == 3) band[myrb + k + 2] = (float)n2;
      }
    }

    // ---- deferred Q apply: chunked 16-deep prefetch, FLOAT (bounded) ----
    VM_FENCE();  // drain prior sweep's Q stores before reloading
    {
      float qw0 = Qg[lo * NN + lane];
      float qw1 = Qg[(lo + 1) * NN + lane];
      float qw2 = Qg[(lo + 2) * NN + lane];
      int done = 0;
      while (done < nk) {
        const int cnt = (nk - done < 16) ? (nk - done) : 16;
        float p[16];
        #pragma unroll
        for (int u = 0; u < 16; ++u) {  // issue all chunk loads together
          const int kc = lo + done + u + 3;
          p[u] = (u < cnt && kc <= hi) ? Qg[kc * NN + lane] : 0.0f;
        }
        #pragma unroll
        for (int u = 0; u < 16; ++u) {
          if (u < cnt) {
            const int i = done + u;
            const float u0 = recT[i], r1 = recY[i], r2 = recZ[i];
            const float t = u0 * (qw0 + r1 * qw1 + r2 * qw2);
            qw0 -= t;
            qw1 -= r1 * t;
            qw2 -= r2 * t;
            Qg[(lo + i) * NN + lane] = qw0;  // col lo+i final
            qw0 = qw1; qw1 = qw2; qw2 = p[u];
          }
        }
        done += 16;
      }
      if (nk == hi - lo) {
        Qg[hi * NN + lane] = qw0;  // flush last window col
      } else {  // collapsed at k = lo+nk: flush pending window cols
        const int k = lo + nk;
        Qg[k * NN + lane] = qw0;
        Qg[(k + 1) * NN + lane] = qw1;
        if (k + 2 <= hi) Qg[(k + 2) * NN + lane] = qw2;
      }
    }
  }

  // band -> dense Schur T (subdiag + upper only)
  for (int r = 0; r < NN; ++r) {
    float v = 0.0f;
    int st = (r >= 1) ? (r - 1) : 0;
    if (lane >= st) v = band[rb_of(r) + lane];
    Tg[r * NN + lane] = v;
  }
}

// ============================================================================
// Kernel 3: Parlett recurrence + symmetrize + Q Fs Q^T. R11-proven: k-sum
// dot loops accumulate in FLOAT (error enters before the 1/gap amplification
// at the same point the proven-safe 1e-5 tol noise does — 100x smaller);
// Sylvester solves stay DOUBLE.
// ============================================================================
__global__ __launch_bounds__(256) void parlett64_kernel(const float* __restrict__ ws,
                                                        float* __restrict__ out) {
  __shared__ float Tfbuf[NN * LDP];
  __shared__ float Fbuf[NN * LDP];
  __shared__ int blkstart[NN];
  __shared__ int bi_of[NN];
  float* Tf = Tfbuf;
  float* Fp = Fbuf;

  const int tid = threadIdx.x;
  const int w = tid >> 6;
  const int lane = tid & 63;
  const size_t mat = blockIdx.x;
  const float* Tg = ws + mat * NN * NN;
  float* dst = out + mat * NN * NN;
  float* Qg = dst;

  #define TF(r, c) ((double)Tf[(r) * LDP + (c)])
  #define TFF(r, c) Tf[(r) * LDP + (c)]
  #define FF(r, c) Fp[(r) * LDP + (c)]

  for (int r = w; r < NN; r += 4) Tf[r * LDP + lane] = Tg[r * NN + lane];
  __syncthreads();

  unsigned long long pair_mask =
      __ballot((lane < NN - 1) && (Tf[(lane + 1) * LDP + lane] != 0.0f));
  unsigned long long start_mask = ~(pair_mask << 1);
  const bool isstart = (start_mask >> lane) & 1ULL;
  const bool ispair = (pair_mask >> lane) & 1ULL;
  double fdiag = 0.0, mymod = 1e300;
  if (isstart) {
    if (ispair) {
      double a = TF(lane, lane), b = TF(lane, lane + 1);
      double c = TF(lane + 1, lane), d = TF(lane + 1, lane + 1);
      fdiag = sqrt(fmax(a * d - b * c, 0.0));
    } else {
      fdiag = fabs(TF(lane, lane));
    }
    mymod = fdiag;
  }
  #pragma unroll
  for (int off = 32; off; off >>= 1) mymod = fmin(mymod, __shfl_xor(mymod, off));
  const double cshift = 1e-6 * mymod;

  if (tid < NN) {
    int nb = (int)__popcll(start_mask & ((1ULL << lane) - 1ULL));
    bi_of[lane] = nb;
    if (isstart) blkstart[nb] = lane;
  }
  for (int r = w; r < NN; r += 4) FF(r, lane) = 0.0f;
  __syncthreads();
  if (tid < NN && isstart) {
    FF(lane, lane) = (float)fdiag;
    if (ispair) FF(lane + 1, lane + 1) = (float)fdiag;
  }
  __syncthreads();

  const int sub = lane & 3;
  const int si = (lane & ~3) | w;

  for (int dist = 1; dist < NN; ++dist) {
    const int sj = si + dist;
    bool active = (sj < NN) && ((start_mask >> si) & 1ULL) && ((start_mask >> sj) & 1ULL);
    if (active) {
      const int p = ((pair_mask >> si) & 1ULL) ? 2 : 1;
      const int q = ((pair_mask >> sj) & 1ULL) ? 2 : 1;
      const int bi0 = bi_of[si], bi1 = bi_of[sj];
      float c00 = 0, c01 = 0, c10 = 0, c11 = 0;  // FLOAT accumulation (R11-proven)
      for (int b = bi0 + sub; b < bi1; b += 4) {
        const int k = blkstart[b];
        const bool kp = (pair_mask >> k) & 1ULL;
        float f00 = FF(si, k);
        float f01 = kp ? FF(si, k + 1) : 0.0f;
        float f10 = (p == 2) ? FF(si + 1, k) : 0.0f;
        float f11 = (p == 2 && kp) ? FF(si + 1, k + 1) : 0.0f;
        float t00 = TFF(k, sj);
        float t01 = (q == 2) ? TFF(k, sj + 1) : 0.0f;
        float t10 = kp ? TFF(k + 1, sj) : 0.0f;
        float t11 = (kp && q == 2) ? TFF(k + 1, sj + 1) : 0.0f;
        c00 += f00 * t00 + f01 * t10;
        c01 += f00 * t01 + f01 * t11;
        c10 += f10 * t00 + f11 * t10;
        c11 += f10 * t01 + f11 * t11;
      }
      for (int b = bi0 + 1 + sub; b <= bi1; b += 4) {
        const int k = blkstart[b];
        const bool kp = (pair_mask >> k) & 1ULL;
        float t00 = TFF(si, k);
        float t01 = kp ? TFF(si, k + 1) : 0.0f;
        float t10 = (p == 2) ? TFF(si + 1, k) : 0.0f;
        float t11 = (p == 2 && kp) ? TFF(si + 1, k + 1) : 0.0f;
        float f00 = FF(k, sj);
        float f01 = (q == 2) ? FF(k, sj + 1) : 0.0f;
        float f10 = kp ? FF(k + 1, sj) : 0.0f;
        float f11 = (kp && q == 2) ? FF(k + 1, sj + 1) : 0.0f;
        c00 -= t00 * f00 + t01 * f10;
        c01 -= t00 * f01 + t01 * f11;
        c10 -= t10 * f00 + t11 * f10;
        c11 -= t10 * f01 + t11 * f11;
      }
      c00 += __shfl_xor(c00, 1); c00 += __shfl_xor(c00, 2);
      c01 += __shfl_xor(c01, 1); c01 += __shfl_xor(c01, 2);
      c10 += __shfl_xor(c10, 1); c10 += __shfl_xor(c10, 2);
      c11 += __shfl_xor(c11, 1); c11 += __shfl_xor(c11, 2);
      if (sub == 0) {
        // solves in DOUBLE (gap-division: the R9-failure amplification point)
        double d00 = (double)c00, d01 = (double)c01;
        double d10 = (double)c10, d11 = (double)c11;
        double x00 = 0, x01 = 0, x10 = 0, x11 = 0;
        if (p == 1 && q == 1) {
          x00 = d00 / guard_d(TF(si, si) - TF(sj, sj));
        } else if (p == 2 && q == 1) {
          double t = TF(sj, sj);
          double m00 = TF(si, si) - t, m01 = TF(si, si + 1);
          double m10 = TF(si + 1, si), m11 = TF(si + 1, si + 1) - t;
          double dd = guard_d(m00 * m11 - m01 * m10);
          x00 = (m11 * d00 - m01 * d10) / dd;
          x10 = (m00 * d10 - m10 * d00) / dd;
        } else if (p == 1 && q == 2) {
          double t = TF(si, si);
          double m00 = t - TF(sj, sj), m01 = -TF(sj, sj + 1);
          double m10 = -TF(sj + 1, sj), m11 = t - TF(sj + 1, sj + 1);
          double dd = guard_d(m00 * m11 - m01 * m10);
          x00 = (d00 * m11 - d01 * m10) / dd;
          x01 = (d01 * m00 - d00 * m01) / dd;
        } else {
          double A00 = TF(si, si), A01 = TF(si, si + 1);
          double A10 = TF(si + 1, si), A11 = TF(si + 1, si + 1);
          double B00 = TF(sj, sj), B01 = TF(sj, sj + 1);
          double B10 = TF(sj + 1, sj), B11 = TF(sj + 1, sj + 1);
          double M[4][5] = {
              {A00 - B00, A01, -B10, 0.0, d00},
              {A10, A11 - B00, 0.0, -B10, d10},
              {-B01, 0.0, A00 - B11, A01, d01},
              {0.0, -B01, A10, A11 - B11, d11}};
          #pragma unroll
          for (int cc = 0; cc < 4; ++cc) {
            #pragma unroll
            for (int rr2 = cc + 1; rr2 < 4; ++rr2) {
              bool sw = fabs(M[rr2][cc]) > fabs(M[cc][cc]);
              #pragma unroll
              for (int t2 = cc; t2 < 5; ++t2) {
                double aa = M[cc][t2], bb = M[rr2][t2];
                M[cc][t2] = sw ? bb : aa;
                M[rr2][t2] = sw ? aa : bb;
              }
            }
            double inv = 1.0 / guard_d(M[cc][cc]);
            #pragma unroll
            for (int rr2 = cc + 1; rr2 < 4; ++rr2) {
              double f2 = M[rr2][cc] * inv;
              #pragma unroll
              for (int t2 = cc; t2 < 5; ++t2) M[rr2][t2] -= f2 * M[cc][t2];
            }
          }
          double z3 = M[3][4] / guard_d(M[3][3]);
          double z2 = (M[2][4] - M[2][3] * z3) / guard_d(M[2][2]);
          double z1 = (M[1][4] - M[1][3] * z3 - M[1][2] * z2) / guard_d(M[1][1]);
          double z0 = (M[0][4] - M[0][3] * z3 - M[0][2] * z2 - M[0][1] * z1) / guard_d(M[0][0]);
          x00 = z0; x10 = z1; x01 = z2; x11 = z3;
        }
        FF(si, sj) = (float)x00;
        if (q == 2) FF(si, sj + 1) = (float)x01;
        if (p == 2) {
          FF(si + 1, sj) = (float)x10;
          if (q == 2) FF(si + 1, sj + 1) = (float)x11;
        }
      }
    }
    __syncthreads();
  }

  {
    const int r = lane;
    for (int j = r + 1 + w; j < NN; j += 4) {
      float v = 0.5f * (FF(r, j) + FF(j, r));
      FF(r, j) = v;
      FF(j, r) = v;
    }
    if (w == 0) FF(r, r) += (float)cshift;
  }
  __syncthreads();

  float* Qs = Tf;  // T dead after Parlett
  for (int c = w; c < NN; c += 4) Qs[lane * LDP + c] = Qg[c * NN + lane];
  __syncthreads();

  float acc[16];
  const int r0 = w * 16;
  #pragma unroll
  for (int i = 0; i < 16; ++i) acc[i] = 0.0f;
  for (int k = 0; k < NN; ++k) {
    float f = FF(k, lane);
    #pragma unroll
    for (int i = 0; i < 16; ++i) acc[i] += Qs[(r0 + i) * LDP + k] * f;
  }
  __syncthreads();
  float* W = Fp;
  #pragma unroll
  for (int i = 0; i < 16; ++i) W[(r0 + i) * LDP + lane] = acc[i];
  __syncthreads();

  #pragma unroll
  for (int i = 0; i < 16; ++i) acc[i] = 0.0f;
  for (int k = 0; k < NN; ++k) {
    float qv = Qs[lane * LDP + k];
    #pragma unroll
    for (int i = 0; i < 16; ++i) acc[i] += W[(r0 + i) * LDP + k] * qv;
  }
  #pragma unroll
  for (int i = 0; i < 16; ++i) dst[(r0 + i) * NN + lane] = acc[i];

  #undef TF
  #undef TFF
  #undef FF
}

extern "C" void kernel_launch(void* const* d_in, const int* in_sizes, int n_in,
                              void* d_out, int out_size, void* d_ws, size_t ws_size,
                              hipStream_t stream) {
  const float* x = (const float*)d_in[0];
  float* out = (float*)d_out;
  float* ws = (float*)d_ws;  // nmat*64*64*4 B = 64 MB dense T handoff
  const int nmat = in_sizes[0] / (NN * NN);  // 4096
  hess64_kernel<<<nmat, 64, 0, stream>>>(x, out, ws);
  qr64_kernel<<<nmat, 64, 0, stream>>>(out, ws);
  parlett64_kernel<<<nmat, 256, 0, stream>>>(ws, out);
}

// Round 14
// 6116.496 us; speedup vs baseline: 1.5932x; 1.0411x over previous
//
#include <hip/hip_runtime.h>

#define NN 64
#define LDP (NN + 1)  // +1 padding: kills the 32/64-way column-access bank conflicts

// Deflation tolerance: 1e-5 (R7/R10/R12-PROVEN; absmax 0.03125). R9 FAILED
// with 1e-4: Parlett's Sylvester solves divide by eigenvalue gaps, amplifying
// erased subdiagonals x10-100 -> 0.469.
#define DEFL_TOL 1e-5

// Packed upper-Hessenberg band with 3 subdiagonals (R10/R12-PROVEN layout).
// Row r stores cols max(0,r-3)..63. 2266 floats = 9064 B -> 16 blocks/CU.
#define BAND_SIZE 2266

__device__ __forceinline__ int rb_of(int r) {
  int t = (r >= 4) ? (((r - 4) * (r - 3)) >> 1) : 0;
  int s = (r >= 3) ? (r - 3) : 0;
  return 64 * r - t - s;
}

__device__ __forceinline__ double guard_d(double p) {
  if (fabs(p) < 1e-280) return (p >= 0.0) ? 1e-280 : -1e-280;
  return p;
}

// Wave-uniform lane read of a double via v_readlane (no LDS, no lgkmcnt).
__device__ __forceinline__ double readlane_d(double v, int l) {
  union { double d; int i[2]; } u;
  u.d = v;
  int a = __builtin_amdgcn_readlane(u.i[0], l);
  int b = __builtin_amdgcn_readlane(u.i[1], l);
  union { double d; int i[2]; } w;
  w.i[0] = a; w.i[1] = b;
  return w.d;
}

// R7-proven: NO explicit LDS fences in the single-wave kernels (one wave per
// block; LDS pipe processes a wave's DS ops in order; compiler preserves
// program order on potentially-aliasing __shared__ accesses). Global Q RMW
// still needs vmcnt ordering:
#define VM_FENCE()                                     \
  do {                                                 \
    asm volatile("s_waitcnt vmcnt(0)" ::: "memory");   \
    __builtin_amdgcn_sched_barrier(0);                 \
  } while (0)

// ============================================================================
// Kernel 1: Hessenberg reduction (R10-proven, unchanged). NORMALIZED FLOAT
// reflector applies (bounded: |w|<=1, u0 in [1,2]); derivation double.
// ============================================================================
__global__ __launch_bounds__(64) void hess64_kernel(const float* __restrict__ x,
                                                    float* __restrict__ out,
                                                    float* __restrict__ ws) {
  __shared__ float Td[NN][LDP];
  __shared__ float vbuf[NN];  // normalized w (|w|<=1), float

  const int lane = threadIdx.x;
  const size_t mat = blockIdx.x;
  const float* src = x + mat * NN * NN;
  float* Qg = out + mat * NN * NN;  // Q^T layout: Qg[c*64+r] = Q[r][c]
  float* Tg = ws + mat * NN * NN;

  for (int r = 0; r < NN; ++r) Td[r][lane] = src[r * NN + lane];
  for (int c = 0; c < NN; ++c) Qg[c * NN + lane] = (c == lane) ? 1.0f : 0.0f;

  for (int k = 0; k <= NN - 3; ++k) {
    const int m = NN - 1 - k;
    double xt = (lane < m) ? (double)Td[k + 1 + lane][k] : 0.0;
    double ss = xt * xt;
    #pragma unroll
    for (int off = 32; off; off >>= 1) ss += __shfl_xor(ss, off);
    double x0 = (double)Td[k + 1][k];
    if (ss > 1e-280) {  // uniform across wave
      double sg = sqrt(ss);
      double beta = (x0 >= 0.0) ? -sg : sg;
      double v0 = x0 - beta;            // |v0| = |x0| + sg >= sg > 0
      double iv0 = 1.0 / v0;
      const float u0f = (float)(fabs(v0) / sg);  // tau*v0^2, in [1,2]
      vbuf[lane] = (lane < m) ? (float)(((lane == 0) ? v0 : xt) * iv0) : 0.0f;
      if (lane >= k + 1) {  // left apply (FLOAT, normalized, bounded)
        const int j = lane;
        float acc = 0.0f;
        for (int t = 0; t < m; ++t) acc += vbuf[t] * Td[k + 1 + t][j];
        float fac = u0f * acc;
        for (int t = 0; t < m; ++t) Td[k + 1 + t][j] -= vbuf[t] * fac;
      }
      if (lane == 0) Td[k + 1][k] = (float)beta;
      if (lane >= 1 && lane < m) Td[k + 1 + lane][k] = 0.0f;
      VM_FENCE();  // Q RMW: iteration k-1's stores vs this iteration's loads
      {  // right apply on T (LDS) and Q (global, coalesced) — FLOAT
        const int r = lane;
        float acc = 0.0f, qa = 0.0f;
        for (int t = 0; t < m; ++t) {
          float wt = vbuf[t];
          acc += Td[r][k + 1 + t] * wt;
          qa += Qg[(k + 1 + t) * NN + r] * wt;
        }
        float facT = u0f * acc, facQ = u0f * qa;
        for (int t = 0; t < m; ++t) {
          float wt = vbuf[t];
          Td[r][k + 1 + t] -= facT * wt;
          Qg[(k + 1 + t) * NN + r] -= facQ * wt;
        }
      }
    }
  }

  for (int r = 0; r < NN; ++r) Tg[r * NN + lane] = Td[r][lane];
}

// ============================================================================
// Kernel 2: Francis double-shift QR on packed band.
// R13: SCALE-FREE FLOAT reflector derivation. The bulge column is normalized
// by an exact power of two 2^E >= max|.| (exponent-bit trick, no divide);
// the scaled values are O(1), so sqrt/div/mul run in FLOAT with zero
// underflow risk (R4's float-chase failure was underflow/early-collapse of
// the handoff, not relative error). The Householder form is scale-invariant:
// tau_s*v_s_i*v_s_j == tau*v_i*v_j, so the scaled (tauf, v0f, fy, fz) feed
// the right apply directly. Numerics: c0/c1/c2 come from FLOAT band storage
// (1e-7 relative noise, proven benign R5-R12); float-accurate transforms add
// error of the same class. What stays DOUBLE: the handoff chain's MAGNITUDE
// (n0 computed+carried in f64; collapse at m<1e-140 == old ss2<1e-280) and
// beta's write (f64 mul by 2^E -> identical denormal behavior).
// ============================================================================
#define TD(r, c) band[rb_of(r) + (c)]

__global__ __launch_bounds__(64) void qr64_kernel(float* __restrict__ out,
                                                  float* __restrict__ ws) {
  __shared__ float band[BAND_SIZE];
  __shared__ float recT[NN], recY[NN], recZ[NN];  // normalized reflector stash

  const int lane = threadIdx.x;
  const int myrb = rb_of(lane);                          // per-lane row base
  const int myrb_m1 = (lane >= 1) ? rb_of(lane - 1) : 0; // row above's base
  const size_t mat = blockIdx.x;
  float* Qg = out + mat * NN * NN;
  float* Tg = ws + mat * NN * NN;

  // dense H -> band
  for (int r = 0; r < NN; ++r) {
    int st = (r >= 3) ? (r - 3) : 0;
    if (lane >= st) band[rb_of(r) + lane] = Tg[r * NN + lane];
  }

  int hi = NN - 1;
  int its = 0, total = 0;
  while (hi > 0) {
    bool small = false;
    if (lane >= 1 && lane <= hi) {  // float scan: 1e-7 noise on a 1e-5 threshold
      float s = fabsf(band[myrb_m1 + lane - 1]) + fabsf(band[myrb + lane]);
      if (s == 0.0f) s = 1e-30f;
      small = fabsf(band[myrb + lane - 1]) <= (float)DEFL_TOL * s;
    }
    unsigned long long msk = __ballot(small) | 1ULL;
    if (hi < 63) msk &= (2ULL << hi) - 1ULL;
    const int lo = 63 - __clzll(msk);
    if (lo > 0) {
      if (lane == 0) TD(lo, lo - 1) = 0.0f;
    }
    if (lo == hi) { hi -= 1; its = 0; continue; }
    if (lo == hi - 1) {  // 2x2 window (cold path, stays double)
      double a = TD(hi - 1, hi - 1), b = TD(hi - 1, hi);
      double c = TD(hi, hi - 1), d = TD(hi, hi);
      double pp = 0.5 * (a - d);
      double disc = pp * pp + b * c;
      if (disc >= 0.0) {  // real pair: rotate to triangular
        double sq = sqrt(disc);
        double mid = 0.5 * (a + d);
        double lam = mid + ((mid >= 0.0) ? sq : -sq);
        double u0 = b, u1 = lam - a;
        double w0 = lam - d, w1 = c;
        double nu = u0 * u0 + u1 * u1, nw = w0 * w0 + w1 * w1;
        double cs, sn;
        if (nu >= nw && nu > 1e-280) { double n2 = sqrt(nu); cs = u0 / n2; sn = u1 / n2; }
        else if (nw > 1e-280) { double n2 = sqrt(nw); cs = w0 / n2; sn = w1 / n2; }
        else { cs = 1.0; sn = 0.0; }
        {
          const int j = lane;
          const int jmin = (hi >= 2) ? (hi - 2) : 0;  // cols < hi-2 exact 0
          if (j >= jmin) {
            double r0 = TD(hi - 1, j), r1 = TD(hi, j);
            TD(hi - 1, j) = (float)(cs * r0 + sn * r1);
            TD(hi, j) = (float)(cs * r1 - sn * r0);
          }
        }
        {
          const int r = lane;
          if (r <= hi) {
            double c0 = TD(r, hi - 1), c1 = TD(r, hi);
            TD(r, hi - 1) = (float)(cs * c0 + sn * c1);
            TD(r, hi) = (float)(cs * c1 - sn * c0);
          }
        }
        VM_FENCE();  // drain prior deferred-Q stores before Q RMW
        {
          const int r = lane;
          double q0 = (double)Qg[(hi - 1) * NN + r], q1 = (double)Qg[hi * NN + r];
          Qg[(hi - 1) * NN + r] = (float)(cs * q0 + sn * q1);
          Qg[hi * NN + r] = (float)(cs * q1 - sn * q0);
        }
        if (lane == 0) TD(hi, hi - 1) = 0.0f;
      }
      hi -= 2; its = 0; continue;
    }
    ++its; ++total;
    if (its > 40 || total > 2000) {  // safety: force deflation
      if (lane == 0) TD(hi, hi - 1) = 0.0f;
      hi -= 1; its = 0; continue;
    }
    double sa, sb, sc2, sd2;
    if (its == 10 || its == 20 || its == 30) {  // exceptional shift
      double sx = fabs((double)TD(hi, hi - 1)) + fabs((double)TD(hi - 1, hi - 2));
      sa = 0.75 * sx + (double)TD(hi, hi); sb = -0.4375 * sx; sc2 = sx; sd2 = sa;
    } else {
      sa = TD(hi - 1, hi - 1); sb = TD(hi - 1, hi);
      sc2 = TD(hi, hi - 1); sd2 = TD(hi, hi);
    }
    double tr = sa + sd2;
    double det = sa * sd2 - sb * sc2;
    double h11 = TD(lo, lo), h12 = TD(lo, lo + 1), h21 = TD(lo + 1, lo);
    double h22 = TD(lo + 1, lo + 1), h32 = TD(lo + 2, lo + 1);
    double cvx = h11 * h11 + h12 * h21 - tr * h11 + det;
    double cvy = h21 * (h11 + h22 - tr);
    double cvz = h21 * h32;

    int nk = hi - lo;  // reflectors recorded this sweep (uniform register)
    for (int k = lo; k <= hi - 1; ++k) {  // bulge chase
      const int rbk = rb_of(k), rbk1 = rb_of(k + 1), rbk2 = rb_of(k + 2);
      const int nr = (k + 2 <= hi) ? 3 : 2;
      const double vx = cvx, vy = cvy, vz = (nr == 3) ? cvz : 0.0;
      // --- scale-free float derivation (R13) ---
      const double mmax = fmax(fabs(vx), fmax(fabs(vy), fabs(vz)));
      if (mmax < 1e-140) { nk = k - lo; break; }  // == old ss2 < 1e-280
      const long long mb =
          __double_as_longlong(mmax) & 0x7FF0000000000000LL;
      const double sdn = __longlong_as_double(0x7FE0000000000000LL - mb);  // 2^-E
      const double inv_s = __longlong_as_double(mb);                       // 2^+E
      const float fx = (float)(vx * sdn);   // max |.| in [1,2)
      const float fy = (float)(vy * sdn);
      const float fz = (float)(vz * sdn);
      const float ss2f = fx * fx + fy * fy + fz * fz;  // in [1, 12]
      const float sgf = sqrtf(ss2f);
      const float betaf = (fx >= 0.0f) ? -sgf : sgf;
      const float v0f = fx - betaf;                 // |v0f| = |fx|+sgf >= 1
      const float tauf = 1.0f / (ss2f - betaf * fx);  // denom in [1, ~18]
      const float iv0f = 1.0f / v0f;
      const float u0f = tauf * v0f * v0f;           // in [1,2]
      const float r1f = fy * iv0f;                  // |.| <= 1
      const float r2f = fz * iv0f;                  // |.| <= 1
      if (lane == 0) { recT[k - lo] = u0f; recY[k - lo] = r1f; recZ[k - lo] = r2f; }
      const int jlo = (k > lo) ? k : lo;
      if (lane >= jlo) {  // left apply — FLOAT normalized (bounded)
        const int j = lane;
        float t0 = band[rbk + j], t1 = band[rbk1 + j];
        float t2v = (nr == 3) ? band[rbk2 + j] : 0.0f;
        float tt = u0f * (t0 + r1f * t1 + r2f * t2v);
        band[rbk + j] = t0 - tt;
        band[rbk1 + j] = t1 - r1f * tt;
        if (nr == 3) band[rbk2 + j] = t2v - r2f * tt;
      }
      if (lane == 0 && k > lo) {  // exact bulge zeros (col k-1)
        band[rbk + (k - 1)] = (float)((double)betaf * inv_s);  // unscale beta
        band[rbk1 + (k - 1)] = 0.0f;
        if (nr == 3) band[rbk2 + (k - 1)] = 0.0f;
      }
      const int rmax = (k + 3 <= hi) ? (k + 3) : hi;
      // right apply: scale-free form n = c - (tau_s*(sum c*v_s))*v_s.
      // n0 (the handoff) in DOUBLE (absolute-magnitude chain); n1/n2 float.
      const double tauD = (double)tauf, v0D = (double)v0f;
      const double v1D = (double)fy, v2D = (double)fz;
      double n0 = 0.0;
      float n1 = 0.0f, n2 = 0.0f;
      if (lane <= rmax) {
        const float c0f = band[myrb + k];
        const float c1f = band[myrb + k + 1];
        const float c2f = (nr == 3) ? band[myrb + k + 2] : 0.0f;
        const double tt = tauD * ((double)c0f * v0D + (double)c1f * v1D +
                                  (double)c2f * v2D);
        n0 = (double)c0f - tt * v0D;
        const float ttf = (float)tt;
        n1 = c1f - ttf * fy;
        n2 = c2f - ttf * fz;
      }
      {  // register handoff of next bulge column (DOUBLE magnitude chain)
        const int ly = (k + 2 <= 63) ? (k + 2) : 0;
        const int lz = (k + 3 <= hi) ? (k + 3) : 0;
        cvx = readlane_d(n0, k + 1);
        cvy = readlane_d(n0, ly);
        cvz = readlane_d(n0, lz);
      }
      if (lane <= rmax) {
        band[myrb + k] = (float)n0;
        band[myrb + k + 1] = n1;
        if (nr == 3) band[myrb + k + 2] = n2;
      }
    }

    // ---- deferred Q apply: chunked 16-deep prefetch, FLOAT (bounded) ----
    VM_FENCE();  // drain prior sweep's Q stores before reloading
    {
      float qw0 = Qg[lo * NN + lane];
      float qw1 = Qg[(lo + 1) * NN + lane];
      float qw2 = Qg[(lo + 2) * NN + lane];
      int done = 0;
      while (done < nk) {
        const int cnt = (nk - done < 16) ? (nk - done) : 16;
        float p[16];
        #pragma unroll
        for (int u = 0; u < 16; ++u) {  // issue all chunk loads together
          const int kc = lo + done + u + 3;
          p[u] = (u < cnt && kc <= hi) ? Qg[kc * NN + lane] : 0.0f;
        }
        #pragma unroll
        for (int u = 0; u < 16; ++u) {
          if (u < cnt) {
            const int i = done + u;
            const float u0 = recT[i], r1 = recY[i], r2 = recZ[i];
            const float t = u0 * (qw0 + r1 * qw1 + r2 * qw2);
            qw0 -= t;
            qw1 -= r1 * t;
            qw2 -= r2 * t;
            Qg[(lo + i) * NN + lane] = qw0;  // col lo+i final
            qw0 = qw1; qw1 = qw2; qw2 = p[u];
          }
        }
        done += 16;
      }
      if (nk == hi - lo) {
        Qg[hi * NN + lane] = qw0;  // flush last window col
      } else {  // collapsed at k = lo+nk: flush pending window cols
        const int k = lo + nk;
        Qg[k * NN + lane] = qw0;
        Qg[(k + 1) * NN + lane] = qw1;
        if (k + 2 <= hi) Qg[(k + 2) * NN + lane] = qw2;
      }
    }
  }

  // band -> dense Schur T (subdiag + upper only)
  for (int r = 0; r < NN; ++r) {
    float v = 0.0f;
    int st = (r >= 1) ? (r - 1) : 0;
    if (lane >= st) v = band[rb_of(r) + lane];
    Tg[r * NN + lane] = v;
  }
}

// ============================================================================
// Kernel 3: Parlett recurrence + symmetrize + Q Fs Q^T (R11/R12-proven,
// unchanged): FLOAT k-sum dots, DOUBLE Sylvester solves.
// ============================================================================
__global__ __launch_bounds__(256) void parlett64_kernel(const float* __restrict__ ws,
                                                        float* __restrict__ out) {
  __shared__ float Tfbuf[NN * LDP];
  __shared__ float Fbuf[NN * LDP];
  __shared__ int blkstart[NN];
  __shared__ int bi_of[NN];
  float* Tf = Tfbuf;
  float* Fp = Fbuf;

  const int tid = threadIdx.x;
  const int w = tid >> 6;
  const int lane = tid & 63;
  const size_t mat = blockIdx.x;
  const float* Tg = ws + mat * NN * NN;
  float* dst = out + mat * NN * NN;
  float* Qg = dst;

  #define TF(r, c) ((double)Tf[(r) * LDP + (c)])
  #define TFF(r, c) Tf[(r) * LDP + (c)]
  #define FF(r, c) Fp[(r) * LDP + (c)]

  for (int r = w; r < NN; r += 4) Tf[r * LDP + lane] = Tg[r * NN + lane];
  __syncthreads();

  unsigned long long pair_mask =
      __ballot((lane < NN - 1) && (Tf[(lane + 1) * LDP + lane] != 0.0f));
  unsigned long long start_mask = ~(pair_mask << 1);
  const bool isstart = (start_mask >> lane) & 1ULL;
  const bool ispair = (pair_mask >> lane) & 1ULL;
  double fdiag = 0.0, mymod = 1e300;
  if (isstart) {
    if (ispair) {
      double a = TF(lane, lane), b = TF(lane, lane + 1);
      double c = TF(lane + 1, lane), d = TF(lane + 1, lane + 1);
      fdiag = sqrt(fmax(a * d - b * c, 0.0));
    } else {
      fdiag = fabs(TF(lane, lane));
    }
    mymod = fdiag;
  }
  #pragma unroll
  for (int off = 32; off; off >>= 1) mymod = fmin(mymod, __shfl_xor(mymod, off));
  const double cshift = 1e-6 * mymod;

  if (tid < NN) {
    int nb = (int)__popcll(start_mask & ((1ULL << lane) - 1ULL));
    bi_of[lane] = nb;
    if (isstart) blkstart[nb] = lane;
  }
  for (int r = w; r < NN; r += 4) FF(r, lane) = 0.0f;
  __syncthreads();
  if (tid < NN && isstart) {
    FF(lane, lane) = (float)fdiag;
    if (ispair) FF(lane + 1, lane + 1) = (float)fdiag;
  }
  __syncthreads();

  const int sub = lane & 3;
  const int si = (lane & ~3) | w;

  for (int dist = 1; dist < NN; ++dist) {
    const int sj = si + dist;
    bool active = (sj < NN) && ((start_mask >> si) & 1ULL) && ((start_mask >> sj) & 1ULL);
    if (active) {
      const int p = ((pair_mask >> si) & 1ULL) ? 2 : 1;
      const int q = ((pair_mask >> sj) & 1ULL) ? 2 : 1;
      const int bi0 = bi_of[si], bi1 = bi_of[sj];
      float c00 = 0, c01 = 0, c10 = 0, c11 = 0;  // FLOAT accumulation (R11-proven)
      for (int b = bi0 + sub; b < bi1; b += 4) {
        const int k = blkstart[b];
        const bool kp = (pair_mask >> k) & 1ULL;
        float f00 = FF(si, k);
        float f01 = kp ? FF(si, k + 1) : 0.0f;
        float f10 = (p == 2) ? FF(si + 1, k) : 0.0f;
        float f11 = (p == 2 && kp) ? FF(si + 1, k + 1) : 0.0f;
        float t00 = TFF(k, sj);
        float t01 = (q == 2) ? TFF(k, sj + 1) : 0.0f;
        float t10 = kp ? TFF(k + 1, sj) : 0.0f;
        float t11 = (kp && q == 2) ? TFF(k + 1, sj + 1) : 0.0f;
        c00 += f00 * t00 + f01 * t10;
        c01 += f00 * t01 + f01 * t11;
        c10 += f10 * t00 + f11 * t10;
        c11 += f10 * t01 + f11 * t11;
      }
      for (int b = bi0 + 1 + sub; b <= bi1; b += 4) {
        const int k = blkstart[b];
        const bool kp = (pair_mask >> k) & 1ULL;
        float t00 = TFF(si, k);
        float t01 = kp ? TFF(si, k + 1) : 0.0f;
        float t10 = (p == 2) ? TFF(si + 1, k) : 0.0f;
        float t11 = (p == 2 && kp) ? TFF(si + 1, k + 1) : 0.0f;
        float f00 = FF(k, sj);
        float f01 = (q == 2) ? FF(k, sj + 1) : 0.0f;
        float f10 = kp ? FF(k + 1, sj) : 0.0f;
        float f11 = (kp && q == 2) ? FF(k + 1, sj + 1) : 0.0f;
        c00 -= t00 * f00 + t01 * f10;
        c01 -= t00 * f01 + t01 * f11;
        c10 -= t10 * f00 + t11 * f10;
        c11 -= t10 * f01 + t11 * f11;
      }
      c00 += __shfl_xor(c00, 1); c00 += __shfl_xor(c00, 2);
      c01 += __shfl_xor(c01, 1); c01 += __shfl_xor(c01, 2);
      c10 += __shfl_xor(c10, 1); c10 += __shfl_xor(c10, 2);
      c11 += __shfl_xor(c11, 1); c11 += __shfl_xor(c11, 2);
      if (sub == 0) {
        // solves in DOUBLE (gap-division: the R9-failure amplification point)
        double d00 = (double)c00, d01 = (double)c01;
        double d10 = (double)c10, d11 = (double)c11;
        double x00 = 0, x01 = 0, x10 = 0, x11 = 0;
        if (p == 1 && q == 1) {
          x00 = d00 / guard_d(TF(si, si) - TF(sj, sj));
        } else if (p == 2 && q == 1) {
          double t = TF(sj, sj);
          double m00 = TF(si, si) - t, m01 = TF(si, si + 1);
          double m10 = TF(si + 1, si), m11 = TF(si + 1, si + 1) - t;
          double dd = guard_d(m00 * m11 - m01 * m10);
          x00 = (m11 * d00 - m01 * d10) / dd;
          x10 = (m00 * d10 - m10 * d00) / dd;
        } else if (p == 1 && q == 2) {
          double t = TF(si, si);
          double m00 = t - TF(sj, sj), m01 = -TF(sj, sj + 1);
          double m10 = -TF(sj + 1, sj), m11 = t - TF(sj + 1, sj + 1);
          double dd = guard_d(m00 * m11 - m01 * m10);
          x00 = (d00 * m11 - d01 * m10) / dd;
          x01 = (d01 * m00 - d00 * m01) / dd;
        } else {
          double A00 = TF(si, si), A01 = TF(si, si + 1);
          double A10 = TF(si + 1, si), A11 = TF(si + 1, si + 1);
          double B00 = TF(sj, sj), B01 = TF(sj, sj + 1);
          double B10 = TF(sj + 1, sj), B11 = TF(sj + 1, sj + 1);
          double M[4][5] = {
              {A00 - B00, A01, -B10, 0.0, d00},
              {A10, A11 - B00, 0.0, -B10, d10},
              {-B01, 0.0, A00 - B11, A01, d01},
              {0.0, -B01, A10, A11 - B11, d11}};
          #pragma unroll
          for (int cc = 0; cc < 4; ++cc) {
            #pragma unroll
            for (int rr2 = cc + 1; rr2 < 4; ++rr2) {
              bool sw = fabs(M[rr2][cc]) > fabs(M[cc][cc]);
              #pragma unroll
              for (int t2 = cc; t2 < 5; ++t2) {
                double aa = M[cc][t2], bb = M[rr2][t2];
                M[cc][t2] = sw ? bb : aa;
                M[rr2][t2] = sw ? aa : bb;
              }
            }
            double inv = 1.0 / guard_d(M[cc][cc]);
            #pragma unroll
            for (int rr2 = cc + 1; rr2 < 4; ++rr2) {
              double f2 = M[rr2][cc] * inv;
              #pragma unroll
              for (int t2 = cc; t2 < 5; ++t2) M[rr2][t2] -= f2 * M[cc][t2];
            }
          }
          double z3 = M[3][4] / guard_d(M[3][3]);
          double z2 = (M[2][4] - M[2][3] * z3) / guard_d(M[2][2]);
          double z1 = (M[1][4] - M[1][3] * z3 - M[1][2] * z2) / guard_d(M[1][1]);
          double z0 = (M[0][4] - M[0][3] * z3 - M[0][2] * z2 - M[0][1] * z1) / guard_d(M[0][0]);
          x00 = z0; x10 = z1; x01 = z2; x11 = z3;
        }
        FF(si, sj) = (float)x00;
        if (q == 2) FF(si, sj + 1) = (float)x01;
        if (p == 2) {
          FF(si + 1, sj) = (float)x10;
          if (q == 2) FF(si + 1, sj + 1) = (float)x11;
        }
      }
    }
    __syncthreads();
  }

  {
    const int r = lane;
    for (int j = r + 1 + w; j < NN; j += 4) {
      float v = 0.5f * (FF(r, j) + FF(j, r));
      FF(r, j) = v;
      FF(j, r) = v;
    }
    if (w == 0) FF(r, r) += (float)cshift;
  }
  __syncthreads();

  float* Qs = Tf;  // T dead after Parlett
  for (int c = w; c < NN; c += 4) Qs[lane * LDP + c] = Qg[c * NN + lane];
  __syncthreads();

  float acc[16];
  const int r0 = w * 16;
  #pragma unroll
  for (int i = 0; i < 16; ++i) acc[i] = 0.0f;
  for (int k = 0; k < NN; ++k) {
    float f = FF(k, lane);
    #pragma unroll
    for (int i = 0; i < 16; ++i) acc[i] += Qs[(r0 + i) * LDP + k] * f;
  }
  __syncthreads();
  float* W = Fp;
  #pragma unroll
  for (int i = 0; i < 16; ++i) W[(r0 + i) * LDP + lane] = acc[i];
  __syncthreads();

  #pragma unroll
  for (int i = 0; i < 16; ++i) acc[i] = 0.0f;
  for (int k = 0; k < NN; ++k) {
    float qv = Qs[lane * LDP + k];
    #pragma unroll
    for (int i = 0; i < 16; ++i) acc[i] += W[(r0 + i) * LDP + k] * qv;
  }
  #pragma unroll
  for (int i = 0; i < 16; ++i) dst[(r0 + i) * NN + lane] = acc[i];

  #undef TF
  #undef TFF
  #undef FF
}

extern "C" void kernel_launch(void* const* d_in, const int* in_sizes, int n_in,
                              void* d_out, int out_size, void* d_ws, size_t ws_size,
                              hipStream_t stream) {
  const float* x = (const float*)d_in[0];
  float* out = (float*)d_out;
  float* ws = (float*)d_ws;  // nmat*64*64*4 B = 64 MB dense T handoff
  const int nmat = in_sizes[0] / (NN * NN);  // 4096
  hess64_kernel<<<nmat, 64, 0, stream>>>(x, out, ws);
  qr64_kernel<<<nmat, 64, 0, stream>>>(out, ws);
  parlett64_kernel<<<nmat, 256, 0, stream>>>(ws, out);
}